// Round 6
// baseline (428.846 us; speedup 1.0000x reference)
//
#include <hip/hip_runtime.h>

// VectorQuantizer: z [16,4096,256] f32, embedding [1024,256] f32
// out (f32, flat): z_q[16777216] | vq_loss[1] | commitment_loss[1] | idxs-as-float[65536]

#define ROWS 65536
#define EDIM 256
#define NEMB 1024
#define OUT_VQ  16777216
#define OUT_CM  16777217
#define OUT_IDX 16777218
#define MARGIN  1.5f
#define RB 8

typedef __attribute__((ext_vector_type(8))) short bf16x8;
typedef __attribute__((ext_vector_type(4))) float f32x4;

__device__ inline unsigned short f2bf(float x) {
  unsigned u = __builtin_bit_cast(unsigned, x);
  unsigned r = (u + 0x7fff + ((u >> 16) & 1)) >> 16;
  return (unsigned short)r;
}
__device__ inline bf16x8 pack8(float4 a, float4 b) {
  bf16x8 r;
  r[0] = (short)f2bf(a.x); r[1] = (short)f2bf(a.y);
  r[2] = (short)f2bf(a.z); r[3] = (short)f2bf(a.w);
  r[4] = (short)f2bf(b.x); r[5] = (short)f2bf(b.y);
  r[6] = (short)f2bf(b.z); r[7] = (short)f2bf(b.w);
  return r;
}
__device__ inline void gload_lds16(const void* g, void* l) {
  __builtin_amdgcn_global_load_lds((const __attribute__((address_space(1))) unsigned int*)g,
                                   (__attribute__((address_space(3))) unsigned int*)l,
                                   16, 0, 0);
}

// ---------------- eprep: emb -> bf16 hi, e2 (R1 rounding order), cnt reset ----------------
__global__ __launch_bounds__(256) void eprep_kernel(const float* __restrict__ emb,
                                                    unsigned short* __restrict__ ehi,
                                                    float* __restrict__ e2,
                                                    int* __restrict__ cnt) {
  int c = blockIdx.x * 256 + threadIdx.x;   // 1024 threads, one code row each
  if (c == 0) cnt[0] = 0;
  const float4* p = (const float4*)(emb + (size_t)c * EDIM);
  unsigned short* eh = ehi + (size_t)c * EDIM;
  float s = 0.f;
  #pragma unroll 8
  for (int j = 0; j < EDIM / 4; ++j) {
    float4 v = p[j];
    s += v.x * v.x; s += v.y * v.y; s += v.z * v.z; s += v.w * v.w;
    uint2 ph;
    ph.x = (unsigned)f2bf(v.x) | ((unsigned)f2bf(v.y) << 16);
    ph.y = (unsigned)f2bf(v.z) | ((unsigned)f2bf(v.w) << 16);
    *(uint2*)(eh + j * 4) = ph;
  }
  e2[c] = s;
}

// ---------------- 1-pass MFMA argmax: A converted in-reg from fp32 z, B dbuf gload_lds --
// BM=64 rows/block, 256 thr (4 waves: wr rows32, wc cols64). 32 phases (8 ncI x 4 kb).
// B tile [128 codes][64 k] shorts, XOR-swizzled (16B quad ^= row&7) both sides (rule 21).
__global__ __launch_bounds__(256, 3) void argmax_kernel(
    const float* __restrict__ z, const unsigned short* __restrict__ ehi,
    const float* __restrict__ e2, int* __restrict__ idxs,
    int* __restrict__ cnt, int* __restrict__ worklist) {
  __shared__ short tiles[2][128 * 64];   // 32 KB double-buffered B

  const int tid  = threadIdx.x;
  const int w    = tid >> 6;      // wave 0..3
  const int lane = tid & 63;
  const int wr   = w >> 1;        // 0..1: 32-row group
  const int wc   = w & 1;         // 0..1: 64-col group
  const int q    = lane >> 4;     // k-group 0..3
  const int lr   = lane & 15;
  const int row0 = blockIdx.x * 64;
  const int l8   = lane >> 3;     // 0..7 (staging row-in-chunk)
  const int sq   = (lane & 7) ^ l8;  // pre-swizzled source quad (involution)

  // ---- A fragments: 64 rows x 256 k, fp32 -> bf16 in registers (read z ONCE) ----
  bf16x8 areg[2][8];
  #pragma unroll
  for (int ms = 0; ms < 2; ++ms) {
    const float4* zb = (const float4*)(z + (size_t)(row0 + wr * 32 + ms * 16 + lr) * EDIM) + q * 2;
    #pragma unroll
    for (int ks = 0; ks < 8; ++ks)
      areg[ms][ks] = pack8(zb[ks * 8], zb[ks * 8 + 1]);
  }

  float b1[8], b2[8]; int i1[8];
  #pragma unroll
  for (int s = 0; s < 8; ++s) { b1[s] = -3.4e38f; b2[s] = -3.4e38f; i1[s] = 0; }

  // stage B tile chunk: buffer b, codes nc..nc+127, k-offset ko..ko+63
  auto stage = [&](int b, int nc, int ko) {
    #pragma unroll
    for (int j = 0; j < 4; ++j) {
      int rbase = j * 32 + w * 8;
      const unsigned short* g = ehi + (size_t)(nc + rbase + l8) * EDIM + ko + (sq << 3);
      gload_lds16(g, &tiles[b][rbase * 64]);
    }
  };

  int buf = 0;
  stage(0, 0, 0);
  __syncthreads();

  for (int ncI = 0; ncI < 8; ++ncI) {
    const int nc = ncI * 128;
    f32x4 acc[2][4];
    #pragma unroll
    for (int ms = 0; ms < 2; ++ms)
      #pragma unroll
      for (int n = 0; n < 4; ++n)
        acc[ms][n] = (f32x4){0.f, 0.f, 0.f, 0.f};

    #pragma unroll
    for (int kb = 0; kb < 4; ++kb) {
      int p = ncI * 4 + kb;
      if (p + 1 < 32) {                   // prefetch next phase into other buffer
        int pn = p + 1;
        stage(buf ^ 1, (pn >> 2) * 128, (pn & 3) * 64);
      }
      #pragma unroll
      for (int ks = 0; ks < 2; ++ks) {
        const int so = (((ks << 2) + q) ^ (lr & 7)) << 3;   // swizzled 16B slot (shorts)
        bf16x8 bfr[4];
        #pragma unroll
        for (int n = 0; n < 4; ++n)
          bfr[n] = *(const bf16x8*)&tiles[buf][(wc * 64 + n * 16 + lr) * 64 + so];
        #pragma unroll
        for (int ms = 0; ms < 2; ++ms)
          #pragma unroll
          for (int n = 0; n < 4; ++n)
            acc[ms][n] = __builtin_amdgcn_mfma_f32_16x16x32_bf16(
                areg[ms][kb * 2 + ks], bfr[n], acc[ms][n], 0, 0, 0);
      }
      __syncthreads();   // drains stage loads (vmcnt0 by compiler) + all waves done with buf
      buf ^= 1;
    }

    // epilogue: running top-2 per row-slot  (sim' = e2 - 2*dot; z2 row-constant)
    #pragma unroll
    for (int n = 0; n < 4; ++n) {
      int c = nc + wc * 64 + n * 16 + lr;
      float e2v = e2[c];
      #pragma unroll
      for (int ms = 0; ms < 2; ++ms)
        #pragma unroll
        for (int r = 0; r < 4; ++r) {
          float sim = fmaf(acc[ms][n][r], -2.0f, e2v);
          int s = ms * 4 + r;
          bool gt = sim > b1[s];
          b2[s] = fmaxf(b2[s], gt ? b1[s] : sim);
          if (gt) { b1[s] = sim; i1[s] = c; }
        }
    }
  }

  // cross-lane reduce over the 16 col-lanes (masks 1,2,4,8), idx tie-break min
  #pragma unroll
  for (int mask = 1; mask <= 8; mask <<= 1) {
    #pragma unroll
    for (int s = 0; s < 8; ++s) {
      float ov1 = __shfl_xor(b1[s], mask);
      int   oi  = __shfl_xor(i1[s], mask);
      float ov2 = __shfl_xor(b2[s], mask);
      float nb2 = fmaxf(fmaxf(b2[s], ov2), fminf(b1[s], ov1));
      bool take = (ov1 > b1[s]) || (ov1 == b1[s] && oi < i1[s]);
      if (take) { b1[s] = ov1; i1[s] = oi; }
      b2[s] = nb2;
    }
  }

  __syncthreads();   // done with GEMM tiles; reuse LDS
  float* rv1 = (float*)&tiles[0][0];          // 64 rows
  int*   ri1 = (int*)&tiles[0][256];
  float* rv2 = (float*)&tiles[0][512];
  if (wc == 0 && lr == 0) {
    #pragma unroll
    for (int s = 0; s < 8; ++s) {
      int R = wr * 32 + (s >> 2) * 16 + q * 4 + (s & 3);
      rv1[R] = b1[s]; ri1[R] = i1[s]; rv2[R] = b2[s];
    }
  }
  __syncthreads();
  if (wc == 1 && lr == 0) {
    #pragma unroll
    for (int s = 0; s < 8; ++s) {
      int R = wr * 32 + (s >> 2) * 16 + q * 4 + (s & 3);
      float av1 = rv1[R]; int ai = ri1[R]; float av2 = rv2[R];
      float m2 = fmaxf(fmaxf(av2, b2[s]), fminf(av1, b1[s]));
      bool take = (b1[s] > av1) || (b1[s] == av1 && i1[s] < ai);
      float m1 = take ? b1[s] : av1;
      int   mi = take ? i1[s] : ai;
      idxs[row0 + R] = mi;
      if (m1 - m2 < MARGIN) {
        int pp = atomicAdd(cnt, 1);
        worklist[pp] = row0 + R;
      }
    }
  }
}

// ---------------- exact fp32 rescue, 8 rows/batch, z-read hoisted across codes ----------
// per k4: 4 global 16B (emb) + 8 LDS b128 (z bcast) + 128 fma  -> VALU-bound
__global__ __launch_bounds__(256) void rescue_kernel(const float* __restrict__ z,
                                                     const float* __restrict__ emb,
                                                     const float* __restrict__ e2,
                                                     int* __restrict__ idxs,
                                                     const int* __restrict__ cnt,
                                                     const int* __restrict__ worklist) {
  __shared__ float zr[RB][EDIM];     // 8 KB
  __shared__ float z2s[RB];
  __shared__ int   rows_s[RB];
  __shared__ float rv[RB][256];      // 8 KB
  __shared__ int   ri[RB][256];      // 8 KB
  const int tid = threadIdx.x;
  const float4* z4 = (const float4*)z;
  const int n = cnt[0];

  for (int base = blockIdx.x * RB; base < n; base += gridDim.x * RB) {
    const int nr = min(RB, n - base);
    for (int i = tid; i < nr * 64; i += 256) {
      int r = i >> 6, k4 = i & 63;
      int row = worklist[base + r];
      ((float4*)zr[r])[k4] = z4[(size_t)row * 64 + k4];
    }
    if (tid < nr) rows_s[tid] = worklist[base + tid];
    __syncthreads();
    if (tid < nr) {    // per-row ||z||^2, R1-sequential rounding
      float s = 0.f;
      const float4* p = (const float4*)zr[tid];
      for (int k = 0; k < 64; ++k) {
        float4 v = p[k];
        s += v.x * v.x; s += v.y * v.y; s += v.z * v.z; s += v.w * v.w;
      }
      z2s[tid] = s;
    }
    __syncthreads();

    // dot[cc][r], k ascending xyzw per (row,code) -> bit-identical to R1 rescue
    float dot[4][RB];
    #pragma unroll
    for (int cc = 0; cc < 4; ++cc)
      #pragma unroll
      for (int r = 0; r < RB; ++r) dot[cc][r] = 0.f;

    const float4* e40 = (const float4*)(emb + (size_t)(0 * 256 + tid) * EDIM);
    const float4* e41 = (const float4*)(emb + (size_t)(1 * 256 + tid) * EDIM);
    const float4* e42 = (const float4*)(emb + (size_t)(2 * 256 + tid) * EDIM);
    const float4* e43 = (const float4*)(emb + (size_t)(3 * 256 + tid) * EDIM);

    for (int k4 = 0; k4 < 64; ++k4) {
      float4 b0 = e40[k4], b1v = e41[k4], b2v = e42[k4], b3 = e43[k4];
      #pragma unroll
      for (int r = 0; r < RB; ++r) {
        float4 a = ((const float4*)zr[r])[k4];   // LDS broadcast, 1 b128 per r
        dot[0][r] = fmaf(a.x, b0.x, dot[0][r]);
        dot[0][r] = fmaf(a.y, b0.y, dot[0][r]);
        dot[0][r] = fmaf(a.z, b0.z, dot[0][r]);
        dot[0][r] = fmaf(a.w, b0.w, dot[0][r]);
        dot[1][r] = fmaf(a.x, b1v.x, dot[1][r]);
        dot[1][r] = fmaf(a.y, b1v.y, dot[1][r]);
        dot[1][r] = fmaf(a.z, b1v.z, dot[1][r]);
        dot[1][r] = fmaf(a.w, b1v.w, dot[1][r]);
        dot[2][r] = fmaf(a.x, b2v.x, dot[2][r]);
        dot[2][r] = fmaf(a.y, b2v.y, dot[2][r]);
        dot[2][r] = fmaf(a.z, b2v.z, dot[2][r]);
        dot[2][r] = fmaf(a.w, b2v.w, dot[2][r]);
        dot[3][r] = fmaf(a.x, b3.x, dot[3][r]);
        dot[3][r] = fmaf(a.y, b3.y, dot[3][r]);
        dot[3][r] = fmaf(a.z, b3.z, dot[3][r]);
        dot[3][r] = fmaf(a.w, b3.w, dot[3][r]);
      }
    }

    float bv[RB]; int bi[RB];
    #pragma unroll
    for (int r = 0; r < RB; ++r) { bv[r] = -3.4e38f; bi[r] = 0; }
    #pragma unroll
    for (int cc = 0; cc < 4; ++cc) {
      int c = cc * 256 + tid;
      #pragma unroll
      for (int r = 0; r < RB; ++r) {
        float t = z2s[r] + e2[c];
        float s = fmaf(dot[cc][r], -2.0f, t);
        if (s > bv[r] || (s == bv[r] && c < bi[r])) { bv[r] = s; bi[r] = c; }
      }
    }

    #pragma unroll
    for (int r = 0; r < RB; ++r) { rv[r][tid] = bv[r]; ri[r][tid] = bi[r]; }
    __syncthreads();
    for (int sN = 128; sN > 0; sN >>= 1) {
      if (tid < sN) {
        #pragma unroll
        for (int r = 0; r < RB; ++r) {
          float ov = rv[r][tid + sN]; int oi = ri[r][tid + sN];
          if (ov > rv[r][tid] || (ov == rv[r][tid] && oi < ri[r][tid])) {
            rv[r][tid] = ov; ri[r][tid] = oi;
          }
        }
      }
      __syncthreads();
    }
    if (tid < nr) idxs[rows_s[tid]] = ri[tid][0];
    __syncthreads();
  }
}

// ---------------- gather z_q + squared-diff partial sums + idxf ----------------
__global__ __launch_bounds__(256) void gather_kernel(
    const float* __restrict__ z, const float* __restrict__ emb,
    const int* __restrict__ idxs, float* __restrict__ out,
    float* __restrict__ partials, float* __restrict__ idxf) {
  const int tid = threadIdx.x;
  const int b = blockIdx.x;            // 1024 blocks, 64 rows each
  const float4* z4 = (const float4*)z;
  float4* q4 = (float4*)out;

  if (tid < 64) {
    int r2 = b * 64 + tid;
    idxf[r2] = (float)idxs[r2];
  }

  float acc = 0.f;
  #pragma unroll
  for (int i = 0; i < 16; ++i) {
    int f = b * 4096 + tid + 256 * i;  // float4 index
    int row = f >> 6;
    int c4 = f & 63;
    int e = idxs[row];
    float4 ev = *(const float4*)&emb[(size_t)e * EDIM + 4 * c4];
    float4 zv = z4[f];
    q4[f] = ev;
    float dx = ev.x - zv.x, dy = ev.y - zv.y, dz = ev.z - zv.z, dw = ev.w - zv.w;
    acc += dx * dx + dy * dy + dz * dz + dw * dw;
  }
  __shared__ float red[256];
  red[tid] = acc;
  __syncthreads();
  #pragma unroll
  for (int sN = 128; sN > 0; sN >>= 1) {
    if (tid < sN) red[tid] += red[tid + sN];
    __syncthreads();
  }
  if (tid == 0) partials[b] = red[0];
}

__global__ void finalize_kernel(const float* __restrict__ partials,
                                float* __restrict__ out) {
  if (threadIdx.x == 0 && blockIdx.x == 0) {
    double s = 0.0;
    for (int i = 0; i < 1024; ++i) s += (double)partials[i];
    float m = (float)(s / 16777216.0);
    out[OUT_VQ] = m;
    out[OUT_CM] = 0.25f * m;
  }
}

extern "C" void kernel_launch(void* const* d_in, const int* in_sizes, int n_in,
                              void* d_out, int out_size, void* d_ws, size_t ws_size,
                              hipStream_t stream) {
  const float* z   = (const float*)d_in[0];
  const float* emb = (const float*)d_in[1];
  float* out = (float*)d_out;

  // ws: ehi 512KB | e2 4KB | idxs 256KB | partials 4KB | cnt 16B | worklist 256KB
  unsigned short* ehi = (unsigned short*)d_ws;
  float* e2       = (float*)(ehi + 262144);
  int*   idxs     = (int*)(e2 + 1024);
  float* partials = (float*)(idxs + 65536);
  int*   cnt      = (int*)(partials + 1024);
  int*   worklist = cnt + 4;

  eprep_kernel<<<NEMB / 256, 256, 0, stream>>>(emb, ehi, e2, cnt);
  argmax_kernel<<<ROWS / 64, 256, 0, stream>>>(z, ehi, e2, idxs, cnt, worklist);
  rescue_kernel<<<1024, 256, 0, stream>>>(z, emb, e2, idxs, cnt, worklist);
  gather_kernel<<<1024, 256, 0, stream>>>(z, emb, idxs, out, partials, out + OUT_IDX);
  finalize_kernel<<<1, 64, 0, stream>>>(partials, out);
}

// Round 7
// 282.402 us; speedup vs baseline: 1.5186x; 1.5186x over previous
//
#include <hip/hip_runtime.h>

// VectorQuantizer: z [16,4096,256] f32, embedding [1024,256] f32
// out (f32, flat): z_q[16777216] | vq_loss[1] | commitment_loss[1] | idxs-as-float[65536]

#define ROWS 65536
#define EDIM 256
#define NEMB 1024
#define OUT_VQ  16777216
#define OUT_CM  16777217
#define OUT_IDX 16777218
#define MARGIN  1.5f
#define RB 4

typedef __attribute__((ext_vector_type(8))) short bf16x8;
typedef __attribute__((ext_vector_type(4))) float f32x4;

__device__ inline unsigned short f2bf(float x) {
  unsigned u = __builtin_bit_cast(unsigned, x);
  unsigned r = (u + 0x7fff + ((u >> 16) & 1)) >> 16;
  return (unsigned short)r;
}
__device__ inline bf16x8 pack8(float4 a, float4 b) {
  bf16x8 r;
  r[0] = (short)f2bf(a.x); r[1] = (short)f2bf(a.y);
  r[2] = (short)f2bf(a.z); r[3] = (short)f2bf(a.w);
  r[4] = (short)f2bf(b.x); r[5] = (short)f2bf(b.y);
  r[6] = (short)f2bf(b.z); r[7] = (short)f2bf(b.w);
  return r;
}
__device__ inline void gload_lds16(const void* g, void* l) {
  __builtin_amdgcn_global_load_lds((const __attribute__((address_space(1))) unsigned int*)g,
                                   (__attribute__((address_space(3))) unsigned int*)l,
                                   16, 0, 0);
}

// ---------------- eprep: emb -> bf16 hi, e2 (R1 rounding order), cnt reset ----------------
__global__ __launch_bounds__(256) void eprep_kernel(const float* __restrict__ emb,
                                                    unsigned short* __restrict__ ehi,
                                                    float* __restrict__ e2,
                                                    int* __restrict__ cnt) {
  int c = blockIdx.x * 256 + threadIdx.x;   // 1024 threads, one code row each
  if (c == 0) cnt[0] = 0;
  const float4* p = (const float4*)(emb + (size_t)c * EDIM);
  unsigned short* eh = ehi + (size_t)c * EDIM;
  float s = 0.f;
  #pragma unroll 8
  for (int j = 0; j < EDIM / 4; ++j) {
    float4 v = p[j];
    s += v.x * v.x; s += v.y * v.y; s += v.z * v.z; s += v.w * v.w;
    uint2 ph;
    ph.x = (unsigned)f2bf(v.x) | ((unsigned)f2bf(v.y) << 16);
    ph.y = (unsigned)f2bf(v.z) | ((unsigned)f2bf(v.w) << 16);
    *(uint2*)(eh + j * 4) = ph;
  }
  e2[c] = s;
}

// ---------------- etrans: embT[k][c] = emb[c][k] (fp32), 64x64 LDS tiles ----------------
__global__ __launch_bounds__(256) void etrans_kernel(const float* __restrict__ emb,
                                                     float* __restrict__ embT) {
  __shared__ float tile[64][65];
  const int bc = blockIdx.x & 15;   // 16 code-tiles
  const int bk = blockIdx.x >> 4;   // 4 k-tiles
  const int c0 = bc * 64, k0 = bk * 64;
  const int r = threadIdx.x >> 2;   // 0..63
  const int q = threadIdx.x & 3;    // 0..3
  #pragma unroll
  for (int j = 0; j < 4; ++j) {
    int kq = q + j * 4;             // float4 col 0..15
    float4 v = *(const float4*)&emb[(size_t)(c0 + r) * EDIM + k0 + kq * 4];
    tile[r][kq * 4 + 0] = v.x; tile[r][kq * 4 + 1] = v.y;
    tile[r][kq * 4 + 2] = v.z; tile[r][kq * 4 + 3] = v.w;
  }
  __syncthreads();
  #pragma unroll
  for (int j = 0; j < 4; ++j) {
    int cq = q + j * 4;             // float4 col in c-dim
    float4 w;
    w.x = tile[cq * 4 + 0][r]; w.y = tile[cq * 4 + 1][r];
    w.z = tile[cq * 4 + 2][r]; w.w = tile[cq * 4 + 3][r];
    *(float4*)&embT[(size_t)(k0 + r) * NEMB + c0 + cq * 4] = w;
  }
}

// ---------------- 1-pass MFMA argmax: A converted in-reg from fp32 z, B dbuf gload_lds --
// (unchanged from round 6 — validated)
__global__ __launch_bounds__(256, 3) void argmax_kernel(
    const float* __restrict__ z, const unsigned short* __restrict__ ehi,
    const float* __restrict__ e2, int* __restrict__ idxs,
    int* __restrict__ cnt, int* __restrict__ worklist) {
  __shared__ short tiles[2][128 * 64];   // 32 KB double-buffered B

  const int tid  = threadIdx.x;
  const int w    = tid >> 6;      // wave 0..3
  const int lane = tid & 63;
  const int wr   = w >> 1;        // 0..1: 32-row group
  const int wc   = w & 1;         // 0..1: 64-col group
  const int q    = lane >> 4;     // k-group 0..3
  const int lr   = lane & 15;
  const int row0 = blockIdx.x * 64;
  const int l8   = lane >> 3;     // 0..7 (staging row-in-chunk)
  const int sq   = (lane & 7) ^ l8;  // pre-swizzled source quad (involution)

  // ---- A fragments: 64 rows x 256 k, fp32 -> bf16 in registers (read z ONCE) ----
  bf16x8 areg[2][8];
  #pragma unroll
  for (int ms = 0; ms < 2; ++ms) {
    const float4* zb = (const float4*)(z + (size_t)(row0 + wr * 32 + ms * 16 + lr) * EDIM) + q * 2;
    #pragma unroll
    for (int ks = 0; ks < 8; ++ks)
      areg[ms][ks] = pack8(zb[ks * 8], zb[ks * 8 + 1]);
  }

  float b1[8], b2[8]; int i1[8];
  #pragma unroll
  for (int s = 0; s < 8; ++s) { b1[s] = -3.4e38f; b2[s] = -3.4e38f; i1[s] = 0; }

  auto stage = [&](int b, int nc, int ko) {
    #pragma unroll
    for (int j = 0; j < 4; ++j) {
      int rbase = j * 32 + w * 8;
      const unsigned short* g = ehi + (size_t)(nc + rbase + l8) * EDIM + ko + (sq << 3);
      gload_lds16(g, &tiles[b][rbase * 64]);
    }
  };

  int buf = 0;
  stage(0, 0, 0);
  __syncthreads();

  for (int ncI = 0; ncI < 8; ++ncI) {
    const int nc = ncI * 128;
    f32x4 acc[2][4];
    #pragma unroll
    for (int ms = 0; ms < 2; ++ms)
      #pragma unroll
      for (int n = 0; n < 4; ++n)
        acc[ms][n] = (f32x4){0.f, 0.f, 0.f, 0.f};

    #pragma unroll
    for (int kb = 0; kb < 4; ++kb) {
      int p = ncI * 4 + kb;
      if (p + 1 < 32) {
        int pn = p + 1;
        stage(buf ^ 1, (pn >> 2) * 128, (pn & 3) * 64);
      }
      #pragma unroll
      for (int ks = 0; ks < 2; ++ks) {
        const int so = (((ks << 2) + q) ^ (lr & 7)) << 3;   // swizzled 16B slot (shorts)
        bf16x8 bfr[4];
        #pragma unroll
        for (int n = 0; n < 4; ++n)
          bfr[n] = *(const bf16x8*)&tiles[buf][(wc * 64 + n * 16 + lr) * 64 + so];
        #pragma unroll
        for (int ms = 0; ms < 2; ++ms)
          #pragma unroll
          for (int n = 0; n < 4; ++n)
            acc[ms][n] = __builtin_amdgcn_mfma_f32_16x16x32_bf16(
                areg[ms][kb * 2 + ks], bfr[n], acc[ms][n], 0, 0, 0);
      }
      __syncthreads();
      buf ^= 1;
    }

    // epilogue: running top-2 per row-slot  (sim' = e2 - 2*dot; z2 row-constant)
    #pragma unroll
    for (int n = 0; n < 4; ++n) {
      int c = nc + wc * 64 + n * 16 + lr;
      float e2v = e2[c];
      #pragma unroll
      for (int ms = 0; ms < 2; ++ms)
        #pragma unroll
        for (int r = 0; r < 4; ++r) {
          float sim = fmaf(acc[ms][n][r], -2.0f, e2v);
          int s = ms * 4 + r;
          bool gt = sim > b1[s];
          b2[s] = fmaxf(b2[s], gt ? b1[s] : sim);
          if (gt) { b1[s] = sim; i1[s] = c; }
        }
    }
  }

  // cross-lane reduce over the 16 col-lanes (masks 1,2,4,8), idx tie-break min
  #pragma unroll
  for (int mask = 1; mask <= 8; mask <<= 1) {
    #pragma unroll
    for (int s = 0; s < 8; ++s) {
      float ov1 = __shfl_xor(b1[s], mask);
      int   oi  = __shfl_xor(i1[s], mask);
      float ov2 = __shfl_xor(b2[s], mask);
      float nb2 = fmaxf(fmaxf(b2[s], ov2), fminf(b1[s], ov1));
      bool take = (ov1 > b1[s]) || (ov1 == b1[s] && oi < i1[s]);
      if (take) { b1[s] = ov1; i1[s] = oi; }
      b2[s] = nb2;
    }
  }

  __syncthreads();
  float* rv1 = (float*)&tiles[0][0];          // 64 rows
  int*   ri1 = (int*)&tiles[0][256];
  float* rv2 = (float*)&tiles[0][512];
  if (wc == 0 && lr == 0) {
    #pragma unroll
    for (int s = 0; s < 8; ++s) {
      int R = wr * 32 + (s >> 2) * 16 + q * 4 + (s & 3);
      rv1[R] = b1[s]; ri1[R] = i1[s]; rv2[R] = b2[s];
    }
  }
  __syncthreads();
  if (wc == 1 && lr == 0) {
    #pragma unroll
    for (int s = 0; s < 8; ++s) {
      int R = wr * 32 + (s >> 2) * 16 + q * 4 + (s & 3);
      float av1 = rv1[R]; int ai = ri1[R]; float av2 = rv2[R];
      float m2 = fmaxf(fmaxf(av2, b2[s]), fminf(av1, b1[s]));
      bool take = (b1[s] > av1) || (b1[s] == av1 && i1[s] < ai);
      float m1 = take ? b1[s] : av1;
      int   mi = take ? i1[s] : ai;
      idxs[row0 + R] = mi;
      if (m1 - m2 < MARGIN) {
        int pp = atomicAdd(cnt, 1);
        worklist[pp] = row0 + R;
      }
    }
  }
}

// ---------------- exact fp32 rescue, coalesced via embT: thread t owns codes 4t..4t+3 ----
// per k: 1 coalesced float4 load (embT row k) + RB LDS broadcasts + 16*RB fma. VALU-bound.
// fma chain per (row,code) is k-ascending scalar -> bit-identical to validated R1 rescue.
__global__ __launch_bounds__(256) void rescue_kernel(const float* __restrict__ z,
                                                     const float* __restrict__ embT,
                                                     const float* __restrict__ e2,
                                                     int* __restrict__ idxs,
                                                     const int* __restrict__ cnt,
                                                     const int* __restrict__ worklist) {
  __shared__ float zr[RB][EDIM];     // 4 KB
  __shared__ float z2s[RB];
  __shared__ int   rows_s[RB];
  __shared__ float rv[RB][256];      // 4 KB
  __shared__ int   ri[RB][256];      // 4 KB
  const int tid = threadIdx.x;
  const float4* z4 = (const float4*)z;
  const float4* eT4 = (const float4*)embT;
  const int n = cnt[0];

  for (int base = blockIdx.x * RB; base < n; base += gridDim.x * RB) {
    const int nr = min(RB, n - base);
    for (int i = tid; i < nr * 64; i += 256) {
      int r = i >> 6, k4 = i & 63;
      int row = worklist[base + r];
      ((float4*)zr[r])[k4] = z4[(size_t)row * 64 + k4];
    }
    if (tid < nr) rows_s[tid] = worklist[base + tid];
    __syncthreads();
    if (tid < nr) {    // per-row ||z||^2, R1-sequential rounding
      float s = 0.f;
      const float4* p = (const float4*)zr[tid];
      for (int k = 0; k < 64; ++k) {
        float4 v = p[k];
        s += v.x * v.x; s += v.y * v.y; s += v.z * v.z; s += v.w * v.w;
      }
      z2s[tid] = s;
    }
    __syncthreads();

    // dot[cc][r]: code c = 4*tid+cc, k ascending -> R1-bit-identical chains
    float dot[4][RB];
    #pragma unroll
    for (int cc = 0; cc < 4; ++cc)
      #pragma unroll
      for (int r = 0; r < RB; ++r) dot[cc][r] = 0.f;

    for (int k4 = 0; k4 < 64; ++k4) {
      float4 a[RB];
      #pragma unroll
      for (int r = 0; r < RB; ++r) a[r] = ((const float4*)zr[r])[k4];  // LDS broadcast
      #pragma unroll
      for (int dk = 0; dk < 4; ++dk) {
        int k = k4 * 4 + dk;
        float4 b = eT4[(size_t)k * 256 + tid];   // embT[k][4t..4t+3], coalesced 1KB/wave
        #pragma unroll
        for (int r = 0; r < RB; ++r) {
          float av = (dk == 0) ? a[r].x : (dk == 1) ? a[r].y : (dk == 2) ? a[r].z : a[r].w;
          dot[0][r] = fmaf(av, b.x, dot[0][r]);
          dot[1][r] = fmaf(av, b.y, dot[1][r]);
          dot[2][r] = fmaf(av, b.z, dot[2][r]);
          dot[3][r] = fmaf(av, b.w, dot[3][r]);
        }
      }
    }

    float bv[RB]; int bi[RB];
    #pragma unroll
    for (int r = 0; r < RB; ++r) { bv[r] = -3.4e38f; bi[r] = 0; }
    #pragma unroll
    for (int cc = 0; cc < 4; ++cc) {
      int c = 4 * tid + cc;
      #pragma unroll
      for (int r = 0; r < RB; ++r) {
        float t = z2s[r] + e2[c];
        float s = fmaf(dot[cc][r], -2.0f, t);
        if (s > bv[r] || (s == bv[r] && c < bi[r])) { bv[r] = s; bi[r] = c; }
      }
    }

    #pragma unroll
    for (int r = 0; r < RB; ++r) { rv[r][tid] = bv[r]; ri[r][tid] = bi[r]; }
    __syncthreads();
    for (int sN = 128; sN > 0; sN >>= 1) {
      if (tid < sN) {
        #pragma unroll
        for (int r = 0; r < RB; ++r) {
          float ov = rv[r][tid + sN]; int oi = ri[r][tid + sN];
          if (ov > rv[r][tid] || (ov == rv[r][tid] && oi < ri[r][tid])) {
            rv[r][tid] = ov; ri[r][tid] = oi;
          }
        }
      }
      __syncthreads();
    }
    if (tid < nr) idxs[rows_s[tid]] = ri[tid][0];
    __syncthreads();
  }
}

// ---------------- gather z_q + squared-diff partial sums + idxf ----------------
__global__ __launch_bounds__(256) void gather_kernel(
    const float* __restrict__ z, const float* __restrict__ emb,
    const int* __restrict__ idxs, float* __restrict__ out,
    float* __restrict__ partials, float* __restrict__ idxf) {
  const int tid = threadIdx.x;
  const int b = blockIdx.x;            // 1024 blocks, 64 rows each
  const float4* z4 = (const float4*)z;
  float4* q4 = (float4*)out;

  if (tid < 64) {
    int r2 = b * 64 + tid;
    idxf[r2] = (float)idxs[r2];
  }

  float acc = 0.f;
  #pragma unroll
  for (int i = 0; i < 16; ++i) {
    int f = b * 4096 + tid + 256 * i;  // float4 index
    int row = f >> 6;
    int c4 = f & 63;
    int e = idxs[row];
    float4 ev = *(const float4*)&emb[(size_t)e * EDIM + 4 * c4];
    float4 zv = z4[f];
    q4[f] = ev;
    float dx = ev.x - zv.x, dy = ev.y - zv.y, dz = ev.z - zv.z, dw = ev.w - zv.w;
    acc += dx * dx + dy * dy + dz * dz + dw * dw;
  }
  __shared__ float red[256];
  red[tid] = acc;
  __syncthreads();
  #pragma unroll
  for (int sN = 128; sN > 0; sN >>= 1) {
    if (tid < sN) red[tid] += red[tid + sN];
    __syncthreads();
  }
  if (tid == 0) partials[b] = red[0];
}

__global__ void finalize_kernel(const float* __restrict__ partials,
                                float* __restrict__ out) {
  if (threadIdx.x == 0 && blockIdx.x == 0) {
    double s = 0.0;
    for (int i = 0; i < 1024; ++i) s += (double)partials[i];
    float m = (float)(s / 16777216.0);
    out[OUT_VQ] = m;
    out[OUT_CM] = 0.25f * m;
  }
}

extern "C" void kernel_launch(void* const* d_in, const int* in_sizes, int n_in,
                              void* d_out, int out_size, void* d_ws, size_t ws_size,
                              hipStream_t stream) {
  const float* z   = (const float*)d_in[0];
  const float* emb = (const float*)d_in[1];
  float* out = (float*)d_out;

  // embT (1MB fp32) lives in the z_q region of d_out; overwritten by gather afterwards
  float* embT = (float*)d_out;

  // ws: ehi 512KB | e2 4KB | idxs 256KB | partials 4KB | cnt 16B | worklist 256KB
  unsigned short* ehi = (unsigned short*)d_ws;
  float* e2       = (float*)(ehi + 262144);
  int*   idxs     = (int*)(e2 + 1024);
  float* partials = (float*)(idxs + 65536);
  int*   cnt      = (int*)(partials + 1024);
  int*   worklist = cnt + 4;

  eprep_kernel<<<NEMB / 256, 256, 0, stream>>>(emb, ehi, e2, cnt);
  etrans_kernel<<<64, 256, 0, stream>>>(emb, embT);
  argmax_kernel<<<ROWS / 64, 256, 0, stream>>>(z, ehi, e2, idxs, cnt, worklist);
  rescue_kernel<<<2048, 256, 0, stream>>>(z, embT, e2, idxs, cnt, worklist);
  gather_kernel<<<1024, 256, 0, stream>>>(z, emb, idxs, out, partials, out + OUT_IDX);
  finalize_kernel<<<1, 64, 0, stream>>>(partials, out);
}

// Round 8
// 278.065 us; speedup vs baseline: 1.5423x; 1.0156x over previous
//
#include <hip/hip_runtime.h>

// VectorQuantizer: z [16,4096,256] f32, embedding [1024,256] f32
// out (f32, flat): z_q[16777216] | vq_loss[1] | commitment_loss[1] | idxs-as-float[65536]

#define ROWS 65536
#define EDIM 256
#define NEMB 1024
#define OUT_VQ  16777216
#define OUT_CM  16777217
#define OUT_IDX 16777218
#define MARGIN  1.5f
#define RB 4

typedef __attribute__((ext_vector_type(8))) short bf16x8;
typedef __attribute__((ext_vector_type(4))) float f32x4;

__device__ inline unsigned short f2bf(float x) {
  unsigned u = __builtin_bit_cast(unsigned, x);
  unsigned r = (u + 0x7fff + ((u >> 16) & 1)) >> 16;
  return (unsigned short)r;
}
__device__ inline bf16x8 pack8(float4 a, float4 b) {
  bf16x8 r;
  r[0] = (short)f2bf(a.x); r[1] = (short)f2bf(a.y);
  r[2] = (short)f2bf(a.z); r[3] = (short)f2bf(a.w);
  r[4] = (short)f2bf(b.x); r[5] = (short)f2bf(b.y);
  r[6] = (short)f2bf(b.z); r[7] = (short)f2bf(b.w);
  return r;
}
__device__ inline void gload_lds16(const void* g, void* l) {
  __builtin_amdgcn_global_load_lds((const __attribute__((address_space(1))) unsigned int*)g,
                                   (__attribute__((address_space(3))) unsigned int*)l,
                                   16, 0, 0);
}

// ---------------- eprep: emb -> bf16 hi, e2 (R1 rounding order), cnt reset ----------------
__global__ __launch_bounds__(256) void eprep_kernel(const float* __restrict__ emb,
                                                    unsigned short* __restrict__ ehi,
                                                    float* __restrict__ e2,
                                                    int* __restrict__ cnt) {
  int c = blockIdx.x * 256 + threadIdx.x;   // 1024 threads, one code row each
  if (c == 0) cnt[0] = 0;
  const float4* p = (const float4*)(emb + (size_t)c * EDIM);
  unsigned short* eh = ehi + (size_t)c * EDIM;
  float s = 0.f;
  #pragma unroll 8
  for (int j = 0; j < EDIM / 4; ++j) {
    float4 v = p[j];
    s += v.x * v.x; s += v.y * v.y; s += v.z * v.z; s += v.w * v.w;
    uint2 ph;
    ph.x = (unsigned)f2bf(v.x) | ((unsigned)f2bf(v.y) << 16);
    ph.y = (unsigned)f2bf(v.z) | ((unsigned)f2bf(v.w) << 16);
    *(uint2*)(eh + j * 4) = ph;
  }
  e2[c] = s;
}

// ---------------- etrans: embT[k][c] = emb[c][k] (fp32), 64x64 LDS tiles ----------------
__global__ __launch_bounds__(256) void etrans_kernel(const float* __restrict__ emb,
                                                     float* __restrict__ embT) {
  __shared__ float tile[64][65];
  const int bc = blockIdx.x & 15;   // 16 code-tiles
  const int bk = blockIdx.x >> 4;   // 4 k-tiles
  const int c0 = bc * 64, k0 = bk * 64;
  const int r = threadIdx.x >> 2;   // 0..63
  const int q = threadIdx.x & 3;    // 0..3
  #pragma unroll
  for (int j = 0; j < 4; ++j) {
    int kq = q + j * 4;             // float4 col 0..15
    float4 v = *(const float4*)&emb[(size_t)(c0 + r) * EDIM + k0 + kq * 4];
    tile[r][kq * 4 + 0] = v.x; tile[r][kq * 4 + 1] = v.y;
    tile[r][kq * 4 + 2] = v.z; tile[r][kq * 4 + 3] = v.w;
  }
  __syncthreads();
  #pragma unroll
  for (int j = 0; j < 4; ++j) {
    int cq = q + j * 4;             // float4 col in c-dim
    float4 w;
    w.x = tile[cq * 4 + 0][r]; w.y = tile[cq * 4 + 1][r];
    w.z = tile[cq * 4 + 2][r]; w.w = tile[cq * 4 + 3][r];
    *(float4*)&embT[(size_t)(k0 + r) * NEMB + c0 + cq * 4] = w;
  }
}

// ---------------- 1-pass MFMA argmax: A in VGPRs, B depth-3 ring w/ counted vmcnt -------
// 32 phases (8 ncI x 4 kb). Phase p: vmcnt(4)[p's stage done, p+1 in flight] -> s_barrier
// -> issue stage(p+2) into buf[(p+2)%3] (WAR-safe: last read phase p-1, pre-barrier)
// -> ds_read buf[p%3] + 16 MFMA. Never drains to 0 in-loop (T3/T4, m218/m201).
__global__ __launch_bounds__(256, 3) void argmax_kernel(
    const float* __restrict__ z, const unsigned short* __restrict__ ehi,
    const float* __restrict__ e2, int* __restrict__ idxs,
    int* __restrict__ cnt, int* __restrict__ worklist) {
  __shared__ short tiles[3][128 * 64];   // 48 KB ring (3 blocks/CU)

  const int tid  = threadIdx.x;
  const int w    = tid >> 6;      // wave 0..3
  const int lane = tid & 63;
  const int wr   = w >> 1;        // 0..1: 32-row group
  const int wc   = w & 1;         // 0..1: 64-col group
  const int q    = lane >> 4;     // k-group 0..3
  const int lr   = lane & 15;
  const int row0 = blockIdx.x * 64;
  const int l8   = lane >> 3;     // 0..7 (staging row-in-chunk)
  const int sq   = (lane & 7) ^ l8;  // pre-swizzled source quad (involution)

  // ---- A fragments: 64 rows x 256 k, fp32 -> bf16 in registers (read z ONCE) ----
  bf16x8 areg[2][8];
  #pragma unroll
  for (int ms = 0; ms < 2; ++ms) {
    const float4* zb = (const float4*)(z + (size_t)(row0 + wr * 32 + ms * 16 + lr) * EDIM) + q * 2;
    #pragma unroll
    for (int ks = 0; ks < 8; ++ks)
      areg[ms][ks] = pack8(zb[ks * 8], zb[ks * 8 + 1]);
  }

  float b1[8], b2[8]; int i1[8];
  #pragma unroll
  for (int s = 0; s < 8; ++s) { b1[s] = -3.4e38f; b2[s] = -3.4e38f; i1[s] = 0; }

  // stage phase s (codes (s>>2)*128, k (s&3)*64) into ring buffer b
  auto stage = [&](int b, int s) {
    const int nc = (s >> 2) * 128;
    const int ko = (s & 3) * 64;
    #pragma unroll
    for (int j = 0; j < 4; ++j) {
      int rbase = j * 32 + w * 8;
      const unsigned short* g = ehi + (size_t)(nc + rbase + l8) * EDIM + ko + (sq << 3);
      gload_lds16(g, &tiles[b][rbase * 64]);
    }
  };

  stage(0, 0);
  stage(1, 1);
  int cur = 0;                     // = phase % 3

  for (int ncI = 0; ncI < 8; ++ncI) {
    f32x4 acc[2][4];
    #pragma unroll
    for (int ms = 0; ms < 2; ++ms)
      #pragma unroll
      for (int n = 0; n < 4; ++n)
        acc[ms][n] = (f32x4){0.f, 0.f, 0.f, 0.f};

    #pragma unroll
    for (int kb = 0; kb < 4; ++kb) {
      // counted wait: own stage(p) complete, stage(p+1)'s 4 loads stay in flight
      if (kb == 3 && ncI == 7) {
        asm volatile("s_waitcnt vmcnt(0)" ::: "memory");
      } else {
        asm volatile("s_waitcnt vmcnt(4)" ::: "memory");
      }
      __builtin_amdgcn_s_barrier();       // raw barrier: no compiler drain
      __builtin_amdgcn_sched_barrier(0);  // pin: nothing crosses the sync point
      const int flat = ncI * 4 + kb;
      if (flat + 2 < 32) {                // prefetch 2 phases ahead
        int nb = cur + 2; if (nb >= 3) nb -= 3;
        stage(nb, flat + 2);
      }
      #pragma unroll
      for (int ks = 0; ks < 2; ++ks) {
        const int so = (((ks << 2) + q) ^ (lr & 7)) << 3;   // swizzled 16B slot (shorts)
        bf16x8 bfr[4];
        #pragma unroll
        for (int n = 0; n < 4; ++n)
          bfr[n] = *(const bf16x8*)&tiles[cur][(wc * 64 + n * 16 + lr) * 64 + so];
        #pragma unroll
        for (int ms = 0; ms < 2; ++ms)
          #pragma unroll
          for (int n = 0; n < 4; ++n)
            acc[ms][n] = __builtin_amdgcn_mfma_f32_16x16x32_bf16(
                areg[ms][kb * 2 + ks], bfr[n], acc[ms][n], 0, 0, 0);
      }
      cur = (cur == 2) ? 0 : cur + 1;
    }

    // epilogue: running top-2 per row-slot  (sim' = e2 - 2*dot; z2 row-constant)
    const int nc = ncI * 128;
    #pragma unroll
    for (int n = 0; n < 4; ++n) {
      int c = nc + wc * 64 + n * 16 + lr;
      float e2v = e2[c];
      #pragma unroll
      for (int ms = 0; ms < 2; ++ms)
        #pragma unroll
        for (int r = 0; r < 4; ++r) {
          float sim = fmaf(acc[ms][n][r], -2.0f, e2v);
          int s = ms * 4 + r;
          bool gt = sim > b1[s];
          b2[s] = fmaxf(b2[s], gt ? b1[s] : sim);
          if (gt) { b1[s] = sim; i1[s] = c; }
        }
    }
  }

  // cross-lane reduce over the 16 col-lanes (masks 1,2,4,8), idx tie-break min
  #pragma unroll
  for (int mask = 1; mask <= 8; mask <<= 1) {
    #pragma unroll
    for (int s = 0; s < 8; ++s) {
      float ov1 = __shfl_xor(b1[s], mask);
      int   oi  = __shfl_xor(i1[s], mask);
      float ov2 = __shfl_xor(b2[s], mask);
      float nb2 = fmaxf(fmaxf(b2[s], ov2), fminf(b1[s], ov1));
      bool take = (ov1 > b1[s]) || (ov1 == b1[s] && oi < i1[s]);
      if (take) { b1[s] = ov1; i1[s] = oi; }
      b2[s] = nb2;
    }
  }

  __syncthreads();   // all stages long done; reuse LDS
  float* rv1 = (float*)&tiles[0][0];          // 64 rows
  int*   ri1 = (int*)&tiles[0][256];
  float* rv2 = (float*)&tiles[0][512];
  if (wc == 0 && lr == 0) {
    #pragma unroll
    for (int s = 0; s < 8; ++s) {
      int R = wr * 32 + (s >> 2) * 16 + q * 4 + (s & 3);
      rv1[R] = b1[s]; ri1[R] = i1[s]; rv2[R] = b2[s];
    }
  }
  __syncthreads();
  if (wc == 1 && lr == 0) {
    #pragma unroll
    for (int s = 0; s < 8; ++s) {
      int R = wr * 32 + (s >> 2) * 16 + q * 4 + (s & 3);
      float av1 = rv1[R]; int ai = ri1[R]; float av2 = rv2[R];
      float m2 = fmaxf(fmaxf(av2, b2[s]), fminf(av1, b1[s]));
      bool take = (b1[s] > av1) || (b1[s] == av1 && i1[s] < ai);
      float m1 = take ? b1[s] : av1;
      int   mi = take ? i1[s] : ai;
      idxs[row0 + R] = mi;
      if (m1 - m2 < MARGIN) {
        int pp = atomicAdd(cnt, 1);
        worklist[pp] = row0 + R;
      }
    }
  }
}

// ---------------- exact fp32 rescue, coalesced via embT: thread t owns codes 4t..4t+3 ----
__global__ __launch_bounds__(256) void rescue_kernel(const float* __restrict__ z,
                                                     const float* __restrict__ embT,
                                                     const float* __restrict__ e2,
                                                     int* __restrict__ idxs,
                                                     const int* __restrict__ cnt,
                                                     const int* __restrict__ worklist) {
  __shared__ float zr[RB][EDIM];     // 4 KB
  __shared__ float z2s[RB];
  __shared__ int   rows_s[RB];
  __shared__ float rv[RB][256];      // 4 KB
  __shared__ int   ri[RB][256];      // 4 KB
  const int tid = threadIdx.x;
  const float4* z4 = (const float4*)z;
  const float4* eT4 = (const float4*)embT;
  const int n = cnt[0];

  for (int base = blockIdx.x * RB; base < n; base += gridDim.x * RB) {
    const int nr = min(RB, n - base);
    for (int i = tid; i < nr * 64; i += 256) {
      int r = i >> 6, k4 = i & 63;
      int row = worklist[base + r];
      ((float4*)zr[r])[k4] = z4[(size_t)row * 64 + k4];
    }
    if (tid < nr) rows_s[tid] = worklist[base + tid];
    __syncthreads();
    if (tid < nr) {    // per-row ||z||^2, R1-sequential rounding
      float s = 0.f;
      const float4* p = (const float4*)zr[tid];
      for (int k = 0; k < 64; ++k) {
        float4 v = p[k];
        s += v.x * v.x; s += v.y * v.y; s += v.z * v.z; s += v.w * v.w;
      }
      z2s[tid] = s;
    }
    __syncthreads();

    // dot[cc][r]: code c = 4*tid+cc, k ascending -> R1-bit-identical chains
    float dot[4][RB];
    #pragma unroll
    for (int cc = 0; cc < 4; ++cc)
      #pragma unroll
      for (int r = 0; r < RB; ++r) dot[cc][r] = 0.f;

    for (int k4 = 0; k4 < 64; ++k4) {
      float4 a[RB];
      #pragma unroll
      for (int r = 0; r < RB; ++r) a[r] = ((const float4*)zr[r])[k4];  // LDS broadcast
      #pragma unroll
      for (int dk = 0; dk < 4; ++dk) {
        int k = k4 * 4 + dk;
        float4 b = eT4[(size_t)k * 256 + tid];   // embT[k][4t..4t+3], coalesced 1KB/wave
        #pragma unroll
        for (int r = 0; r < RB; ++r) {
          float av = (dk == 0) ? a[r].x : (dk == 1) ? a[r].y : (dk == 2) ? a[r].z : a[r].w;
          dot[0][r] = fmaf(av, b.x, dot[0][r]);
          dot[1][r] = fmaf(av, b.y, dot[1][r]);
          dot[2][r] = fmaf(av, b.z, dot[2][r]);
          dot[3][r] = fmaf(av, b.w, dot[3][r]);
        }
      }
    }

    float bv[RB]; int bi[RB];
    #pragma unroll
    for (int r = 0; r < RB; ++r) { bv[r] = -3.4e38f; bi[r] = 0; }
    #pragma unroll
    for (int cc = 0; cc < 4; ++cc) {
      int c = 4 * tid + cc;
      #pragma unroll
      for (int r = 0; r < RB; ++r) {
        float t = z2s[r] + e2[c];
        float s = fmaf(dot[cc][r], -2.0f, t);
        if (s > bv[r] || (s == bv[r] && c < bi[r])) { bv[r] = s; bi[r] = c; }
      }
    }

    #pragma unroll
    for (int r = 0; r < RB; ++r) { rv[r][tid] = bv[r]; ri[r][tid] = bi[r]; }
    __syncthreads();
    for (int sN = 128; sN > 0; sN >>= 1) {
      if (tid < sN) {
        #pragma unroll
        for (int r = 0; r < RB; ++r) {
          float ov = rv[r][tid + sN]; int oi = ri[r][tid + sN];
          if (ov > rv[r][tid] || (ov == rv[r][tid] && oi < ri[r][tid])) {
            rv[r][tid] = ov; ri[r][tid] = oi;
          }
        }
      }
      __syncthreads();
    }
    if (tid < nr) idxs[rows_s[tid]] = ri[tid][0];
    __syncthreads();
  }
}

// ---------------- gather z_q + squared-diff partial sums + idxf ----------------
__global__ __launch_bounds__(256) void gather_kernel(
    const float* __restrict__ z, const float* __restrict__ emb,
    const int* __restrict__ idxs, float* __restrict__ out,
    float* __restrict__ partials, float* __restrict__ idxf) {
  const int tid = threadIdx.x;
  const int b = blockIdx.x;            // 1024 blocks, 64 rows each
  const float4* z4 = (const float4*)z;
  float4* q4 = (float4*)out;

  if (tid < 64) {
    int r2 = b * 64 + tid;
    idxf[r2] = (float)idxs[r2];
  }

  float acc = 0.f;
  #pragma unroll
  for (int i = 0; i < 16; ++i) {
    int f = b * 4096 + tid + 256 * i;  // float4 index
    int row = f >> 6;
    int c4 = f & 63;
    int e = idxs[row];
    float4 ev = *(const float4*)&emb[(size_t)e * EDIM + 4 * c4];
    float4 zv = z4[f];
    q4[f] = ev;
    float dx = ev.x - zv.x, dy = ev.y - zv.y, dz = ev.z - zv.z, dw = ev.w - zv.w;
    acc += dx * dx + dy * dy + dz * dz + dw * dw;
  }
  __shared__ float red[256];
  red[tid] = acc;
  __syncthreads();
  #pragma unroll
  for (int sN = 128; sN > 0; sN >>= 1) {
    if (tid < sN) red[tid] += red[tid + sN];
    __syncthreads();
  }
  if (tid == 0) partials[b] = red[0];
}

__global__ void finalize_kernel(const float* __restrict__ partials,
                                float* __restrict__ out) {
  if (threadIdx.x == 0 && blockIdx.x == 0) {
    double s = 0.0;
    for (int i = 0; i < 1024; ++i) s += (double)partials[i];
    float m = (float)(s / 16777216.0);
    out[OUT_VQ] = m;
    out[OUT_CM] = 0.25f * m;
  }
}

extern "C" void kernel_launch(void* const* d_in, const int* in_sizes, int n_in,
                              void* d_out, int out_size, void* d_ws, size_t ws_size,
                              hipStream_t stream) {
  const float* z   = (const float*)d_in[0];
  const float* emb = (const float*)d_in[1];
  float* out = (float*)d_out;

  // embT (1MB fp32) lives in the z_q region of d_out; overwritten by gather afterwards
  float* embT = (float*)d_out;

  // ws: ehi 512KB | e2 4KB | idxs 256KB | partials 4KB | cnt 16B | worklist 256KB
  unsigned short* ehi = (unsigned short*)d_ws;
  float* e2       = (float*)(ehi + 262144);
  int*   idxs     = (int*)(e2 + 1024);
  float* partials = (float*)(idxs + 65536);
  int*   cnt      = (int*)(partials + 1024);
  int*   worklist = cnt + 4;

  eprep_kernel<<<NEMB / 256, 256, 0, stream>>>(emb, ehi, e2, cnt);
  etrans_kernel<<<64, 256, 0, stream>>>(emb, embT);
  argmax_kernel<<<ROWS / 64, 256, 0, stream>>>(z, ehi, e2, idxs, cnt, worklist);
  rescue_kernel<<<2048, 256, 0, stream>>>(z, embT, e2, idxs, cnt, worklist);
  gather_kernel<<<1024, 256, 0, stream>>>(z, emb, idxs, out, partials, out + OUT_IDX);
  finalize_kernel<<<1, 64, 0, stream>>>(partials, out);
}

// Round 9
// 264.596 us; speedup vs baseline: 1.6208x; 1.0509x over previous
//
#include <hip/hip_runtime.h>

// VectorQuantizer: z [16,4096,256] f32, embedding [1024,256] f32
// out (f32, flat): z_q[16777216] | vq_loss[1] | commitment_loss[1] | idxs-as-float[65536]

#define ROWS 65536
#define EDIM 256
#define NEMB 1024
#define OUT_VQ  16777216
#define OUT_CM  16777217
#define OUT_IDX 16777218
#define MARGIN  1.5f
#define RB 4

typedef __attribute__((ext_vector_type(8))) short bf16x8;
typedef __attribute__((ext_vector_type(4))) float f32x4;

__device__ inline unsigned short f2bf(float x) {
  unsigned u = __builtin_bit_cast(unsigned, x);
  unsigned r = (u + 0x7fff + ((u >> 16) & 1)) >> 16;
  return (unsigned short)r;
}
__device__ inline void gload_lds16(const void* g, void* l) {
  __builtin_amdgcn_global_load_lds((const __attribute__((address_space(1))) unsigned int*)g,
                                   (__attribute__((address_space(3))) unsigned int*)l,
                                   16, 0, 0);
}

// ---------------- zsplit: z -> bf16 hi (stored in d_out z_q region) ----------------
__global__ __launch_bounds__(256) void zsplit_kernel(const float* __restrict__ z,
                                                     unsigned short* __restrict__ zhi) {
  size_t gid = (size_t)blockIdx.x * 256 + threadIdx.x;   // 2,097,152 threads, 8 elems each
  const float4* z4 = (const float4*)z;
  float4 v0 = z4[gid * 2];
  float4 v1 = z4[gid * 2 + 1];
  uint4 ph;
  ph.x = (unsigned)f2bf(v0.x) | ((unsigned)f2bf(v0.y) << 16);
  ph.y = (unsigned)f2bf(v0.z) | ((unsigned)f2bf(v0.w) << 16);
  ph.z = (unsigned)f2bf(v1.x) | ((unsigned)f2bf(v1.y) << 16);
  ph.w = (unsigned)f2bf(v1.z) | ((unsigned)f2bf(v1.w) << 16);
  ((uint4*)zhi)[gid] = ph;
}

// ---------------- eprep: emb -> bf16 hi, e2 (R1 rounding order), cnt reset ----------------
__global__ __launch_bounds__(256) void eprep_kernel(const float* __restrict__ emb,
                                                    unsigned short* __restrict__ ehi,
                                                    float* __restrict__ e2,
                                                    int* __restrict__ cnt) {
  int c = blockIdx.x * 256 + threadIdx.x;   // 1024 threads, one code row each
  if (c == 0) cnt[0] = 0;
  const float4* p = (const float4*)(emb + (size_t)c * EDIM);
  unsigned short* eh = ehi + (size_t)c * EDIM;
  float s = 0.f;
  #pragma unroll 8
  for (int j = 0; j < EDIM / 4; ++j) {
    float4 v = p[j];
    s += v.x * v.x; s += v.y * v.y; s += v.z * v.z; s += v.w * v.w;
    uint2 ph;
    ph.x = (unsigned)f2bf(v.x) | ((unsigned)f2bf(v.y) << 16);
    ph.y = (unsigned)f2bf(v.z) | ((unsigned)f2bf(v.w) << 16);
    *(uint2*)(eh + j * 4) = ph;
  }
  e2[c] = s;
}

// ---------------- etrans: embT[k][c] = emb[c][k] (fp32), 64x64 LDS tiles ----------------
__global__ __launch_bounds__(256) void etrans_kernel(const float* __restrict__ emb,
                                                     float* __restrict__ embT) {
  __shared__ float tile[64][65];
  const int bc = blockIdx.x & 15;   // 16 code-tiles
  const int bk = blockIdx.x >> 4;   // 4 k-tiles
  const int c0 = bc * 64, k0 = bk * 64;
  const int r = threadIdx.x >> 2;   // 0..63
  const int q = threadIdx.x & 3;    // 0..3
  #pragma unroll
  for (int j = 0; j < 4; ++j) {
    int kq = q + j * 4;             // float4 col 0..15
    float4 v = *(const float4*)&emb[(size_t)(c0 + r) * EDIM + k0 + kq * 4];
    tile[r][kq * 4 + 0] = v.x; tile[r][kq * 4 + 1] = v.y;
    tile[r][kq * 4 + 2] = v.z; tile[r][kq * 4 + 3] = v.w;
  }
  __syncthreads();
  #pragma unroll
  for (int j = 0; j < 4; ++j) {
    int cq = q + j * 4;             // float4 col in c-dim
    float4 w;
    w.x = tile[cq * 4 + 0][r]; w.y = tile[cq * 4 + 1][r];
    w.z = tile[cq * 4 + 2][r]; w.w = tile[cq * 4 + 3][r];
    *(float4*)&embT[(size_t)(k0 + r) * NEMB + c0 + cq * 4] = w;
  }
}

// ---------------- 1-pass MFMA argmax, R4-proven structure: 8 waves, BM=128, BN=128 ------
// Per phase (8 ncI x 4 kb): barrier -> stage Ahi+Bhi (32 KB, gload_lds w/ XOR swizzle)
// -> barrier(drain) -> 12 ds_read_b128 + 16 MFMA per wave. e2 lives in LDS: epilogue has
// ZERO vmem (no hidden vmcnt(0) drain). 36 KB LDS -> 2 blocks/CU (grid 512) = 4 waves/SIMD.
__global__ __launch_bounds__(512, 4) void argmax_kernel(
    const unsigned short* __restrict__ zhi, const unsigned short* __restrict__ ehi,
    const float* __restrict__ e2, int* __restrict__ idxs,
    int* __restrict__ cnt, int* __restrict__ worklist) {
  __shared__ short As[128 * 64];   // 16 KB (rows x 64k, XOR-swizzled quads)
  __shared__ short Bs[128 * 64];   // 16 KB (codes x 64k)
  __shared__ float e2s[NEMB];      // 4 KB

  const int tid  = threadIdx.x;
  const int w    = tid >> 6;      // wave 0..7
  const int lane = tid & 63;
  const int wr   = w >> 1;        // 0..3: 32-row group
  const int wc   = w & 1;         // 0..1: 64-col group
  const int q    = lane >> 4;     // k-group 0..3
  const int lr   = lane & 15;
  const int row0 = blockIdx.x * 128;
  const int l8   = lane >> 3;     // 0..7 (staging row-in-chunk)
  const int sq   = (lane & 7) ^ l8;  // pre-swizzled source quad (involution)

  for (int i = tid; i < NEMB; i += 512) e2s[i] = e2[i];

  float b1[8], b2[8]; int i1[8];
  #pragma unroll
  for (int s = 0; s < 8; ++s) { b1[s] = -3.4e38f; b2[s] = -3.4e38f; i1[s] = 0; }

  const int strow = wr * 32;                     // this wave's staging row base
  short* sdst = (w & 1) ? Bs : As;               // even waves stage A, odd stage B

  for (int ncI = 0; ncI < 8; ++ncI) {
    const int nc = ncI * 128;
    const unsigned short* sbase = (w & 1) ? ehi + (size_t)nc * EDIM
                                          : zhi + (size_t)row0 * EDIM;
    f32x4 acc[2][4];
    #pragma unroll
    for (int ms = 0; ms < 2; ++ms)
      #pragma unroll
      for (int n = 0; n < 4; ++n)
        acc[ms][n] = (f32x4){0.f, 0.f, 0.f, 0.f};

    #pragma unroll
    for (int kb = 0; kb < 4; ++kb) {
      const int ko = kb * 64;
      __syncthreads();   // previous phase's ds_reads (and e2s init) done
      #pragma unroll
      for (int j = 0; j < 4; ++j) {
        const int rbase = strow + j * 8;
        gload_lds16(sbase + (size_t)(rbase + l8) * EDIM + ko + (sq << 3),
                    sdst + rbase * 64);
      }
      __syncthreads();   // compiler drains vmcnt before barrier: tiles ready
      #pragma unroll
      for (int ks = 0; ks < 2; ++ks) {
        const int so = (((ks << 2) + q) ^ (lr & 7)) << 3;   // swizzled 16B slot (shorts)
        bf16x8 ah[2];
        #pragma unroll
        for (int ms = 0; ms < 2; ++ms)
          ah[ms] = *(const bf16x8*)&As[(wr * 32 + ms * 16 + lr) * 64 + so];
        bf16x8 bfr[4];
        #pragma unroll
        for (int n = 0; n < 4; ++n)
          bfr[n] = *(const bf16x8*)&Bs[(wc * 64 + n * 16 + lr) * 64 + so];
        #pragma unroll
        for (int ms = 0; ms < 2; ++ms)
          #pragma unroll
          for (int n = 0; n < 4; ++n)
            acc[ms][n] = __builtin_amdgcn_mfma_f32_16x16x32_bf16(ah[ms], bfr[n], acc[ms][n], 0, 0, 0);
      }
    }

    // epilogue: running top-2 per row-slot (sim' = e2 - 2*dot; z2 row-constant). LDS-only.
    #pragma unroll
    for (int n = 0; n < 4; ++n) {
      int c = nc + wc * 64 + n * 16 + lr;
      float e2v = e2s[c];
      #pragma unroll
      for (int ms = 0; ms < 2; ++ms)
        #pragma unroll
        for (int r = 0; r < 4; ++r) {
          float sim = fmaf(acc[ms][n][r], -2.0f, e2v);
          int s = ms * 4 + r;
          bool gt = sim > b1[s];
          b2[s] = fmaxf(b2[s], gt ? b1[s] : sim);
          if (gt) { b1[s] = sim; i1[s] = c; }
        }
    }
  }

  // cross-lane reduce over the 16 col-lanes (masks 1,2,4,8), idx tie-break min
  #pragma unroll
  for (int mask = 1; mask <= 8; mask <<= 1) {
    #pragma unroll
    for (int s = 0; s < 8; ++s) {
      float ov1 = __shfl_xor(b1[s], mask);
      int   oi  = __shfl_xor(i1[s], mask);
      float ov2 = __shfl_xor(b2[s], mask);
      float nb2 = fmaxf(fmaxf(b2[s], ov2), fminf(b1[s], ov1));
      bool take = (ov1 > b1[s]) || (ov1 == b1[s] && oi < i1[s]);
      if (take) { b1[s] = ov1; i1[s] = oi; }
      b2[s] = nb2;
    }
  }

  __syncthreads();   // done with GEMM tiles; reuse As
  float* rv1 = (float*)&As[0];            // 128 floats
  int*   ri1 = (int*)&As[256];
  float* rv2 = (float*)&As[512];
  if (wc == 0 && lr == 0) {
    #pragma unroll
    for (int s = 0; s < 8; ++s) {
      int R = wr * 32 + (s >> 2) * 16 + q * 4 + (s & 3);
      rv1[R] = b1[s]; ri1[R] = i1[s]; rv2[R] = b2[s];
    }
  }
  __syncthreads();
  if (wc == 1 && lr == 0) {
    #pragma unroll
    for (int s = 0; s < 8; ++s) {
      int R = wr * 32 + (s >> 2) * 16 + q * 4 + (s & 3);
      float av1 = rv1[R]; int ai = ri1[R]; float av2 = rv2[R];
      float m2 = fmaxf(fmaxf(av2, b2[s]), fminf(av1, b1[s]));
      bool take = (b1[s] > av1) || (b1[s] == av1 && i1[s] < ai);
      float m1 = take ? b1[s] : av1;
      int   mi = take ? i1[s] : ai;
      idxs[row0 + R] = mi;
      if (m1 - m2 < MARGIN) {
        int pp = atomicAdd(cnt, 1);
        worklist[pp] = row0 + R;
      }
    }
  }
}

// ---------------- exact fp32 rescue, coalesced via embT: thread t owns codes 4t..4t+3 ----
__global__ __launch_bounds__(256) void rescue_kernel(const float* __restrict__ z,
                                                     const float* __restrict__ embT,
                                                     const float* __restrict__ e2,
                                                     int* __restrict__ idxs,
                                                     const int* __restrict__ cnt,
                                                     const int* __restrict__ worklist) {
  __shared__ float zr[RB][EDIM];     // 4 KB
  __shared__ float z2s[RB];
  __shared__ int   rows_s[RB];
  __shared__ float rv[RB][256];      // 4 KB
  __shared__ int   ri[RB][256];      // 4 KB
  const int tid = threadIdx.x;
  const float4* z4 = (const float4*)z;
  const float4* eT4 = (const float4*)embT;
  const int n = cnt[0];

  for (int base = blockIdx.x * RB; base < n; base += gridDim.x * RB) {
    const int nr = min(RB, n - base);
    for (int i = tid; i < nr * 64; i += 256) {
      int r = i >> 6, k4 = i & 63;
      int row = worklist[base + r];
      ((float4*)zr[r])[k4] = z4[(size_t)row * 64 + k4];
    }
    if (tid < nr) rows_s[tid] = worklist[base + tid];
    __syncthreads();
    if (tid < nr) {    // per-row ||z||^2, R1-sequential rounding
      float s = 0.f;
      const float4* p = (const float4*)zr[tid];
      for (int k = 0; k < 64; ++k) {
        float4 v = p[k];
        s += v.x * v.x; s += v.y * v.y; s += v.z * v.z; s += v.w * v.w;
      }
      z2s[tid] = s;
    }
    __syncthreads();

    // dot[cc][r]: code c = 4*tid+cc, k ascending -> R1-bit-identical chains
    float dot[4][RB];
    #pragma unroll
    for (int cc = 0; cc < 4; ++cc)
      #pragma unroll
      for (int r = 0; r < RB; ++r) dot[cc][r] = 0.f;

    for (int k4 = 0; k4 < 64; ++k4) {
      float4 a[RB];
      #pragma unroll
      for (int r = 0; r < RB; ++r) a[r] = ((const float4*)zr[r])[k4];  // LDS broadcast
      #pragma unroll
      for (int dk = 0; dk < 4; ++dk) {
        int k = k4 * 4 + dk;
        float4 b = eT4[(size_t)k * 256 + tid];   // embT[k][4t..4t+3], coalesced 1KB/wave
        #pragma unroll
        for (int r = 0; r < RB; ++r) {
          float av = (dk == 0) ? a[r].x : (dk == 1) ? a[r].y : (dk == 2) ? a[r].z : a[r].w;
          dot[0][r] = fmaf(av, b.x, dot[0][r]);
          dot[1][r] = fmaf(av, b.y, dot[1][r]);
          dot[2][r] = fmaf(av, b.z, dot[2][r]);
          dot[3][r] = fmaf(av, b.w, dot[3][r]);
        }
      }
    }

    float bv[RB]; int bi[RB];
    #pragma unroll
    for (int r = 0; r < RB; ++r) { bv[r] = -3.4e38f; bi[r] = 0; }
    #pragma unroll
    for (int cc = 0; cc < 4; ++cc) {
      int c = 4 * tid + cc;
      #pragma unroll
      for (int r = 0; r < RB; ++r) {
        float t = z2s[r] + e2[c];
        float s = fmaf(dot[cc][r], -2.0f, t);
        if (s > bv[r] || (s == bv[r] && c < bi[r])) { bv[r] = s; bi[r] = c; }
      }
    }

    #pragma unroll
    for (int r = 0; r < RB; ++r) { rv[r][tid] = bv[r]; ri[r][tid] = bi[r]; }
    __syncthreads();
    for (int sN = 128; sN > 0; sN >>= 1) {
      if (tid < sN) {
        #pragma unroll
        for (int r = 0; r < RB; ++r) {
          float ov = rv[r][tid + sN]; int oi = ri[r][tid + sN];
          if (ov > rv[r][tid] || (ov == rv[r][tid] && oi < ri[r][tid])) {
            rv[r][tid] = ov; ri[r][tid] = oi;
          }
        }
      }
      __syncthreads();
    }
    if (tid < nr) idxs[rows_s[tid]] = ri[tid][0];
    __syncthreads();
  }
}

// ---------------- gather z_q + squared-diff partial sums + idxf ----------------
__global__ __launch_bounds__(256) void gather_kernel(
    const float* __restrict__ z, const float* __restrict__ emb,
    const int* __restrict__ idxs, float* __restrict__ out,
    float* __restrict__ partials, float* __restrict__ idxf) {
  const int tid = threadIdx.x;
  const int b = blockIdx.x;            // 1024 blocks, 64 rows each
  const float4* z4 = (const float4*)z;
  float4* q4 = (float4*)out;

  if (tid < 64) {
    int r2 = b * 64 + tid;
    idxf[r2] = (float)idxs[r2];
  }

  float acc = 0.f;
  #pragma unroll
  for (int i = 0; i < 16; ++i) {
    int f = b * 4096 + tid + 256 * i;  // float4 index
    int row = f >> 6;
    int c4 = f & 63;
    int e = idxs[row];
    float4 ev = *(const float4*)&emb[(size_t)e * EDIM + 4 * c4];
    float4 zv = z4[f];
    q4[f] = ev;
    float dx = ev.x - zv.x, dy = ev.y - zv.y, dz = ev.z - zv.z, dw = ev.w - zv.w;
    acc += dx * dx + dy * dy + dz * dz + dw * dw;
  }
  __shared__ float red[256];
  red[tid] = acc;
  __syncthreads();
  #pragma unroll
  for (int sN = 128; sN > 0; sN >>= 1) {
    if (tid < sN) red[tid] += red[tid + sN];
    __syncthreads();
  }
  if (tid == 0) partials[b] = red[0];
}

__global__ void finalize_kernel(const float* __restrict__ partials,
                                float* __restrict__ out) {
  if (threadIdx.x == 0 && blockIdx.x == 0) {
    double s = 0.0;
    for (int i = 0; i < 1024; ++i) s += (double)partials[i];
    float m = (float)(s / 16777216.0);
    out[OUT_VQ] = m;
    out[OUT_CM] = 0.25f * m;
  }
}

extern "C" void kernel_launch(void* const* d_in, const int* in_sizes, int n_in,
                              void* d_out, int out_size, void* d_ws, size_t ws_size,
                              hipStream_t stream) {
  const float* z   = (const float*)d_in[0];
  const float* emb = (const float*)d_in[1];
  float* out = (float*)d_out;

  // d_out z_q region staging: zhi bf16 [0,32MB) ; embT fp32 [32MB,33MB). gather overwrites.
  unsigned short* zhi = (unsigned short*)d_out;
  float* embT = out + 8388608;

  // ws: ehi 512KB | e2 4KB | idxs 256KB | partials 4KB | cnt 16B | worklist 256KB
  unsigned short* ehi = (unsigned short*)d_ws;
  float* e2       = (float*)(ehi + 262144);
  int*   idxs     = (int*)(e2 + 1024);
  float* partials = (float*)(idxs + 65536);
  int*   cnt      = (int*)(partials + 1024);
  int*   worklist = cnt + 4;

  zsplit_kernel<<<8192, 256, 0, stream>>>(z, zhi);
  eprep_kernel<<<NEMB / 256, 256, 0, stream>>>(emb, ehi, e2, cnt);
  etrans_kernel<<<64, 256, 0, stream>>>(emb, embT);
  argmax_kernel<<<ROWS / 128, 512, 0, stream>>>(zhi, ehi, e2, idxs, cnt, worklist);
  rescue_kernel<<<2048, 256, 0, stream>>>(z, embT, e2, idxs, cnt, worklist);
  gather_kernel<<<1024, 256, 0, stream>>>(z, emb, idxs, out, partials, out + OUT_IDX);
  finalize_kernel<<<1, 64, 0, stream>>>(partials, out);
}

// Round 10
// 243.952 us; speedup vs baseline: 1.7579x; 1.0846x over previous
//
#include <hip/hip_runtime.h>

// VectorQuantizer: z [16,4096,256] f32, embedding [1024,256] f32
// out (f32, flat): z_q[16777216] | vq_loss[1] | commitment_loss[1] | idxs-as-float[65536]

#define ROWS 65536
#define EDIM 256
#define NEMB 1024
#define OUT_VQ  16777216
#define OUT_CM  16777217
#define OUT_IDX 16777218
#define MARGIN  1.5f
#define RB 16

typedef __attribute__((ext_vector_type(8))) short bf16x8;
typedef __attribute__((ext_vector_type(4))) float f32x4;

__device__ inline unsigned short f2bf(float x) {
  unsigned u = __builtin_bit_cast(unsigned, x);
  unsigned r = (u + 0x7fff + ((u >> 16) & 1)) >> 16;
  return (unsigned short)r;
}
__device__ inline void gload_lds16(const void* g, void* l) {
  __builtin_amdgcn_global_load_lds((const __attribute__((address_space(1))) unsigned int*)g,
                                   (__attribute__((address_space(3))) unsigned int*)l,
                                   16, 0, 0);
}

// ---------------- zsplit: z -> bf16 hi (stored in d_out z_q region) ----------------
__global__ __launch_bounds__(256) void zsplit_kernel(const float* __restrict__ z,
                                                     unsigned short* __restrict__ zhi) {
  size_t gid = (size_t)blockIdx.x * 256 + threadIdx.x;   // 2,097,152 threads, 8 elems each
  const float4* z4 = (const float4*)z;
  float4 v0 = z4[gid * 2];
  float4 v1 = z4[gid * 2 + 1];
  uint4 ph;
  ph.x = (unsigned)f2bf(v0.x) | ((unsigned)f2bf(v0.y) << 16);
  ph.y = (unsigned)f2bf(v0.z) | ((unsigned)f2bf(v0.w) << 16);
  ph.z = (unsigned)f2bf(v1.x) | ((unsigned)f2bf(v1.y) << 16);
  ph.w = (unsigned)f2bf(v1.z) | ((unsigned)f2bf(v1.w) << 16);
  ((uint4*)zhi)[gid] = ph;
}

// ---------------- eprep: emb -> bf16 hi, e2 (R1 rounding order), cnt reset ----------------
__global__ __launch_bounds__(256) void eprep_kernel(const float* __restrict__ emb,
                                                    unsigned short* __restrict__ ehi,
                                                    float* __restrict__ e2,
                                                    int* __restrict__ cnt) {
  int c = blockIdx.x * 256 + threadIdx.x;   // 1024 threads, one code row each
  if (c == 0) cnt[0] = 0;
  const float4* p = (const float4*)(emb + (size_t)c * EDIM);
  unsigned short* eh = ehi + (size_t)c * EDIM;
  float s = 0.f;
  #pragma unroll 8
  for (int j = 0; j < EDIM / 4; ++j) {
    float4 v = p[j];
    s += v.x * v.x; s += v.y * v.y; s += v.z * v.z; s += v.w * v.w;
    uint2 ph;
    ph.x = (unsigned)f2bf(v.x) | ((unsigned)f2bf(v.y) << 16);
    ph.y = (unsigned)f2bf(v.z) | ((unsigned)f2bf(v.w) << 16);
    *(uint2*)(eh + j * 4) = ph;
  }
  e2[c] = s;
}

// ---------------- etrans: embT[k][c] = emb[c][k] (fp32), 64x64 LDS tiles ----------------
__global__ __launch_bounds__(256) void etrans_kernel(const float* __restrict__ emb,
                                                     float* __restrict__ embT) {
  __shared__ float tile[64][65];
  const int bc = blockIdx.x & 15;   // 16 code-tiles
  const int bk = blockIdx.x >> 4;   // 4 k-tiles
  const int c0 = bc * 64, k0 = bk * 64;
  const int r = threadIdx.x >> 2;   // 0..63
  const int q = threadIdx.x & 3;    // 0..3
  #pragma unroll
  for (int j = 0; j < 4; ++j) {
    int kq = q + j * 4;             // float4 col 0..15
    float4 v = *(const float4*)&emb[(size_t)(c0 + r) * EDIM + k0 + kq * 4];
    tile[r][kq * 4 + 0] = v.x; tile[r][kq * 4 + 1] = v.y;
    tile[r][kq * 4 + 2] = v.z; tile[r][kq * 4 + 3] = v.w;
  }
  __syncthreads();
  #pragma unroll
  for (int j = 0; j < 4; ++j) {
    int cq = q + j * 4;             // float4 col in c-dim
    float4 w;
    w.x = tile[cq * 4 + 0][r]; w.y = tile[cq * 4 + 1][r];
    w.z = tile[cq * 4 + 2][r]; w.w = tile[cq * 4 + 3][r];
    *(float4*)&embT[(size_t)(k0 + r) * NEMB + c0 + cq * 4] = w;
  }
}

// ---------------- barrier-free strip argmax -------------------------------------------
// grid 512: nstrip = b>>6 (128 codes), mchunk = b&63 (1024 rows). XCD note: the 8 blocks
// sharing mchunk have b%8 == mchunk%8 -> same XCD -> zhi rows L2-hit 7/8.
// B-tile [128 codes][256 k] bf16 (64 KB) staged ONCE via gload_lds (quad^(row&7) swizzle),
// then NO barriers: each wave streams 4 iters x 32 rows, A in VGPRs, 128 MFMA/iter.
// Writes per-strip top2 to gtop[row*8+strip]; merge_kernel does the cross-strip argmax.
__global__ __launch_bounds__(512) void argmax_kernel(
    const unsigned short* __restrict__ zhi, const unsigned short* __restrict__ ehi,
    const float* __restrict__ e2, float4* __restrict__ gtop) {
  __shared__ short Bs[128 * 256];   // 64 KB

  const int tid  = threadIdx.x;
  const int w    = tid >> 6;      // wave 0..7
  const int lane = tid & 63;
  const int q    = lane >> 4;     // 0..3
  const int lr   = lane & 15;
  const int b = blockIdx.x;
  const int mchunk = b & 63;
  const int nstrip = b >> 6;
  const int nc = nstrip * 128;
  const int rbase0 = mchunk * 1024;

  // ---- stage B once: instr j writes rows {w*16+j*2, +1} linearly; src pre-swizzled ----
  {
    const int qq = lane & 31;            // quad within row
    const int rj = lane >> 5;            // row within pair
    #pragma unroll
    for (int j = 0; j < 8; ++j) {
      int row = w * 16 + j * 2 + rj;
      int gq = (qq & 24) | ((qq & 7) ^ (row & 7));
      gload_lds16(ehi + (size_t)(nc + row) * EDIM + gq * 8,
                  &Bs[(w * 16 + j * 2) * 256]);
    }
  }

  // per-lane e2 for its 8 columns (constant across iters)
  float e2r[8];
  #pragma unroll
  for (int n = 0; n < 8; ++n) e2r[n] = e2[nc + n * 16 + lr];

  __syncthreads();   // compiler drains vmcnt: B-tile ready. Last barrier in the kernel.

  bf16x8 A[2][8];
  {
    const int rowIt = rbase0 + w * 32;
    #pragma unroll
    for (int ms = 0; ms < 2; ++ms) {
      const unsigned short* zb = zhi + (size_t)(rowIt + ms * 16 + lr) * EDIM + q * 8;
      #pragma unroll
      for (int ks = 0; ks < 8; ++ks)
        A[ms][ks] = *(const bf16x8*)(zb + ks * 32);
    }
  }

  #pragma unroll
  for (int it = 0; it < 4; ++it) {
    const int rowIt = rbase0 + it * 256 + w * 32;
    f32x4 acc[2][8];
    #pragma unroll
    for (int ms = 0; ms < 2; ++ms)
      #pragma unroll
      for (int n = 0; n < 8; ++n)
        acc[ms][n] = (f32x4){0.f, 0.f, 0.f, 0.f};

    #pragma unroll
    for (int ks = 0; ks < 8; ++ks) {
      const int sq = ((ks * 4 + q) & 24) | (((ks * 4 + q) & 7) ^ (lr & 7));
      bf16x8 bfr[8];
      #pragma unroll
      for (int n = 0; n < 8; ++n)
        bfr[n] = *(const bf16x8*)&Bs[(n * 16 + lr) * 256 + sq * 8];
      #pragma unroll
      for (int n = 0; n < 8; ++n)
        #pragma unroll
        for (int ms = 0; ms < 2; ++ms)
          acc[ms][n] = __builtin_amdgcn_mfma_f32_16x16x32_bf16(A[ms][ks], bfr[n], acc[ms][n], 0, 0, 0);
    }

    if (it < 3) {   // A regs dead: load next iter's A; latency hides under epilogue
      const int rowN = rbase0 + (it + 1) * 256 + w * 32;
      #pragma unroll
      for (int ms = 0; ms < 2; ++ms) {
        const unsigned short* zb = zhi + (size_t)(rowN + ms * 16 + lr) * EDIM + q * 8;
        #pragma unroll
        for (int ks = 0; ks < 8; ++ks)
          A[ms][ks] = *(const bf16x8*)(zb + ks * 32);
      }
    }

    // epilogue: top2 over this iter's 32 rows x 128 cols (sim' = e2 - 2*dot)
    float b1[8], b2[8]; int i1[8];
    #pragma unroll
    for (int s = 0; s < 8; ++s) { b1[s] = -3.4e38f; b2[s] = -3.4e38f; i1[s] = 0; }
    #pragma unroll
    for (int n = 0; n < 8; ++n) {
      int c = nc + n * 16 + lr;
      #pragma unroll
      for (int ms = 0; ms < 2; ++ms)
        #pragma unroll
        for (int r = 0; r < 4; ++r) {
          float sim = fmaf(acc[ms][n][r], -2.0f, e2r[n]);
          int s = ms * 4 + r;
          bool gt = sim > b1[s];
          b2[s] = fmaxf(b2[s], gt ? b1[s] : sim);
          if (gt) { b1[s] = sim; i1[s] = c; }
        }
    }
    // cross-lane reduce over 16 col-lanes (masks 1,2,4,8), idx tie-break min
    #pragma unroll
    for (int mask = 1; mask <= 8; mask <<= 1) {
      #pragma unroll
      for (int s = 0; s < 8; ++s) {
        float ov1 = __shfl_xor(b1[s], mask);
        int   oi  = __shfl_xor(i1[s], mask);
        float ov2 = __shfl_xor(b2[s], mask);
        float nb2 = fmaxf(fmaxf(b2[s], ov2), fminf(b1[s], ov1));
        bool take = (ov1 > b1[s]) || (ov1 == b1[s] && oi < i1[s]);
        if (take) { b1[s] = ov1; i1[s] = oi; }
        b2[s] = nb2;
      }
    }
    if (lr == 0) {
      #pragma unroll
      for (int s = 0; s < 8; ++s) {
        int grow = rowIt + (s >> 2) * 16 + q * 4 + (s & 3);   // C-layout row = q*4+reg
        float4 t; t.x = b1[s]; t.y = __int_as_float(i1[s]); t.z = b2[s]; t.w = 0.f;
        gtop[(size_t)grow * 8 + nstrip] = t;
      }
    }
  }
}

// ---------------- merge 8 strip-top2s per row -> idxs + margin worklist ----------------
__global__ __launch_bounds__(256) void merge_kernel(const float4* __restrict__ gtop,
                                                    int* __restrict__ idxs,
                                                    int* __restrict__ cnt,
                                                    int* __restrict__ worklist) {
  int r = blockIdx.x * 256 + threadIdx.x;   // grid 256 -> 65536 rows
  float bv1 = -3.4e38f, bv2 = -3.4e38f; int bi1 = 0;
  #pragma unroll
  for (int s = 0; s < 8; ++s) {
    float4 t = gtop[(size_t)r * 8 + s];
    float v1 = t.x, v2 = t.z; int i = __float_as_int(t.y);
    float nb2 = fmaxf(fmaxf(bv2, v2), fminf(bv1, v1));
    bool take = (v1 > bv1) || (v1 == bv1 && i < bi1);
    if (take) { bv1 = v1; bi1 = i; }
    bv2 = nb2;
  }
  idxs[r] = bi1;
  if (bv1 - bv2 < MARGIN) {
    int p = atomicAdd(cnt, 1);
    worklist[p] = r;
  }
}

// ---------------- exact fp32 rescue, RB=16 rows/batch, coalesced embT ------------------
// embT re-read per block amortized over 16 rows: 512 blocks x 1MB = 0.5GB L2 (~15us),
// balanced against 16K fma/thread (VALU ~14us). Math bit-identical to validated R1 chain.
__global__ __launch_bounds__(256) void rescue_kernel(const float* __restrict__ z,
                                                     const float* __restrict__ embT,
                                                     const float* __restrict__ e2,
                                                     int* __restrict__ idxs,
                                                     const int* __restrict__ cnt,
                                                     const int* __restrict__ worklist) {
  __shared__ float zr[RB][EDIM];     // 16 KB
  __shared__ float z2s[RB];
  __shared__ int   rows_s[RB];
  __shared__ float rv[RB][256];      // 16 KB
  __shared__ int   ri[RB][256];      // 16 KB
  const int tid = threadIdx.x;
  const float4* z4 = (const float4*)z;
  const float4* eT4 = (const float4*)embT;
  const int n = cnt[0];

  for (int base = blockIdx.x * RB; base < n; base += gridDim.x * RB) {
    const int nr = min(RB, n - base);
    for (int i = tid; i < nr * 64; i += 256) {
      int r = i >> 6, k4 = i & 63;
      int row = worklist[base + r];
      ((float4*)zr[r])[k4] = z4[(size_t)row * 64 + k4];
    }
    if (tid < nr) rows_s[tid] = worklist[base + tid];
    __syncthreads();
    if (tid < nr) {    // per-row ||z||^2, R1-sequential rounding
      float s = 0.f;
      const float4* p = (const float4*)zr[tid];
      for (int k = 0; k < 64; ++k) {
        float4 v = p[k];
        s += v.x * v.x; s += v.y * v.y; s += v.z * v.z; s += v.w * v.w;
      }
      z2s[tid] = s;
    }
    __syncthreads();

    // dot[cc][r]: code c = 4*tid+cc, k ascending -> R1-bit-identical chains
    float dot[4][RB];
    #pragma unroll
    for (int cc = 0; cc < 4; ++cc)
      #pragma unroll
      for (int r = 0; r < RB; ++r) dot[cc][r] = 0.f;

    for (int k4 = 0; k4 < 64; ++k4) {
      float4 a[RB];
      #pragma unroll
      for (int r = 0; r < RB; ++r) a[r] = ((const float4*)zr[r])[k4];  // LDS broadcast
      #pragma unroll
      for (int dk = 0; dk < 4; ++dk) {
        int k = k4 * 4 + dk;
        float4 bv = eT4[(size_t)k * 256 + tid];   // embT[k][4t..4t+3], coalesced
        #pragma unroll
        for (int r = 0; r < RB; ++r) {
          float av = (dk == 0) ? a[r].x : (dk == 1) ? a[r].y : (dk == 2) ? a[r].z : a[r].w;
          dot[0][r] = fmaf(av, bv.x, dot[0][r]);
          dot[1][r] = fmaf(av, bv.y, dot[1][r]);
          dot[2][r] = fmaf(av, bv.z, dot[2][r]);
          dot[3][r] = fmaf(av, bv.w, dot[3][r]);
        }
      }
    }

    float bv[RB]; int bi[RB];
    #pragma unroll
    for (int r = 0; r < RB; ++r) { bv[r] = -3.4e38f; bi[r] = 0; }
    #pragma unroll
    for (int cc = 0; cc < 4; ++cc) {
      int c = 4 * tid + cc;
      #pragma unroll
      for (int r = 0; r < RB; ++r) {
        float t = z2s[r] + e2[c];
        float s = fmaf(dot[cc][r], -2.0f, t);
        if (s > bv[r] || (s == bv[r] && c < bi[r])) { bv[r] = s; bi[r] = c; }
      }
    }

    #pragma unroll
    for (int r = 0; r < RB; ++r) { rv[r][tid] = bv[r]; ri[r][tid] = bi[r]; }
    __syncthreads();
    for (int sN = 128; sN > 0; sN >>= 1) {
      if (tid < sN) {
        #pragma unroll
        for (int r = 0; r < RB; ++r) {
          float ov = rv[r][tid + sN]; int oi = ri[r][tid + sN];
          if (ov > rv[r][tid] || (ov == rv[r][tid] && oi < ri[r][tid])) {
            rv[r][tid] = ov; ri[r][tid] = oi;
          }
        }
      }
      __syncthreads();
    }
    if (tid < nr) idxs[rows_s[tid]] = ri[tid][0];
    __syncthreads();
  }
}

// ---------------- gather z_q + squared-diff partial sums + idxf ----------------
__global__ __launch_bounds__(256) void gather_kernel(
    const float* __restrict__ z, const float* __restrict__ emb,
    const int* __restrict__ idxs, float* __restrict__ out,
    float* __restrict__ partials, float* __restrict__ idxf) {
  const int tid = threadIdx.x;
  const int b = blockIdx.x;            // 1024 blocks, 64 rows each
  const float4* z4 = (const float4*)z;
  float4* q4 = (float4*)out;

  if (tid < 64) {
    int r2 = b * 64 + tid;
    idxf[r2] = (float)idxs[r2];
  }

  float acc = 0.f;
  #pragma unroll
  for (int i = 0; i < 16; ++i) {
    int f = b * 4096 + tid + 256 * i;  // float4 index
    int row = f >> 6;
    int c4 = f & 63;
    int e = idxs[row];
    float4 ev = *(const float4*)&emb[(size_t)e * EDIM + 4 * c4];
    float4 zv = z4[f];
    q4[f] = ev;
    float dx = ev.x - zv.x, dy = ev.y - zv.y, dz = ev.z - zv.z, dw = ev.w - zv.w;
    acc += dx * dx + dy * dy + dz * dz + dw * dw;
  }
  __shared__ float red[256];
  red[tid] = acc;
  __syncthreads();
  #pragma unroll
  for (int sN = 128; sN > 0; sN >>= 1) {
    if (tid < sN) red[tid] += red[tid + sN];
    __syncthreads();
  }
  if (tid == 0) partials[b] = red[0];
}

__global__ void finalize_kernel(const float* __restrict__ partials,
                                float* __restrict__ out) {
  if (threadIdx.x == 0 && blockIdx.x == 0) {
    double s = 0.0;
    for (int i = 0; i < 1024; ++i) s += (double)partials[i];
    float m = (float)(s / 16777216.0);
    out[OUT_VQ] = m;
    out[OUT_CM] = 0.25f * m;
  }
}

extern "C" void kernel_launch(void* const* d_in, const int* in_sizes, int n_in,
                              void* d_out, int out_size, void* d_ws, size_t ws_size,
                              hipStream_t stream) {
  const float* z   = (const float*)d_in[0];
  const float* emb = (const float*)d_in[1];
  float* out = (float*)d_out;

  // d_out z_q region (64MB) staging, overwritten by gather afterwards:
  //   zhi bf16 [0,32MB) | embT fp32 [32,33MB) | gtop float4 [36,44MB)
  unsigned short* zhi = (unsigned short*)d_out;
  float* embT = out + 8388608;
  float4* gtop = (float4*)(out + 9437184);

  // ws: ehi 512KB | e2 4KB | idxs 256KB | partials 4KB | cnt 16B | worklist 256KB
  unsigned short* ehi = (unsigned short*)d_ws;
  float* e2       = (float*)(ehi + 262144);
  int*   idxs     = (int*)(e2 + 1024);
  float* partials = (float*)(idxs + 65536);
  int*   cnt      = (int*)(partials + 1024);
  int*   worklist = cnt + 4;

  zsplit_kernel<<<8192, 256, 0, stream>>>(z, zhi);
  eprep_kernel<<<NEMB / 256, 256, 0, stream>>>(emb, ehi, e2, cnt);
  etrans_kernel<<<64, 256, 0, stream>>>(emb, embT);
  argmax_kernel<<<512, 512, 0, stream>>>(zhi, ehi, e2, gtop);
  merge_kernel<<<256, 256, 0, stream>>>(gtop, idxs, cnt, worklist);
  rescue_kernel<<<512, 256, 0, stream>>>(z, embT, e2, idxs, cnt, worklist);
  gather_kernel<<<1024, 256, 0, stream>>>(z, emb, idxs, out, partials, out + OUT_IDX);
  finalize_kernel<<<1, 64, 0, stream>>>(partials, out);
}

// Round 11
// 227.092 us; speedup vs baseline: 1.8884x; 1.0742x over previous
//
#include <hip/hip_runtime.h>

// VectorQuantizer: z [16,4096,256] f32, embedding [1024,256] f32
// out (f32, flat): z_q[16777216] | vq_loss[1] | commitment_loss[1] | idxs-as-float[65536]

#define ROWS 65536
#define EDIM 256
#define NEMB 1024
#define OUT_VQ  16777216
#define OUT_CM  16777217
#define OUT_IDX 16777218
#define MARGIN  1.5f

typedef __attribute__((ext_vector_type(8))) short bf16x8;
typedef __attribute__((ext_vector_type(4))) float f32x4;

__device__ inline unsigned short f2bf(float x) {
  unsigned u = __builtin_bit_cast(unsigned, x);
  unsigned r = (u + 0x7fff + ((u >> 16) & 1)) >> 16;
  return (unsigned short)r;
}
__device__ inline void gload_lds16(const void* g, void* l) {
  __builtin_amdgcn_global_load_lds((const __attribute__((address_space(1))) unsigned int*)g,
                                   (__attribute__((address_space(3))) unsigned int*)l,
                                   16, 0, 0);
}

// ---------------- zsplit: z -> bf16 hi (stored in d_out z_q region) ----------------
__global__ __launch_bounds__(256) void zsplit_kernel(const float* __restrict__ z,
                                                     unsigned short* __restrict__ zhi) {
  size_t gid = (size_t)blockIdx.x * 256 + threadIdx.x;   // 2,097,152 threads, 8 elems each
  const float4* z4 = (const float4*)z;
  float4 v0 = z4[gid * 2];
  float4 v1 = z4[gid * 2 + 1];
  uint4 ph;
  ph.x = (unsigned)f2bf(v0.x) | ((unsigned)f2bf(v0.y) << 16);
  ph.y = (unsigned)f2bf(v0.z) | ((unsigned)f2bf(v0.w) << 16);
  ph.z = (unsigned)f2bf(v1.x) | ((unsigned)f2bf(v1.y) << 16);
  ph.w = (unsigned)f2bf(v1.z) | ((unsigned)f2bf(v1.w) << 16);
  ((uint4*)zhi)[gid] = ph;
}

// ---------------- eprep: emb -> bf16 hi, e2 (R1 rounding order), cnt reset ----------------
__global__ __launch_bounds__(256) void eprep_kernel(const float* __restrict__ emb,
                                                    unsigned short* __restrict__ ehi,
                                                    float* __restrict__ e2,
                                                    int* __restrict__ cnt) {
  int c = blockIdx.x * 256 + threadIdx.x;   // 1024 threads, one code row each
  if (c == 0) cnt[0] = 0;
  const float4* p = (const float4*)(emb + (size_t)c * EDIM);
  unsigned short* eh = ehi + (size_t)c * EDIM;
  float s = 0.f;
  #pragma unroll 8
  for (int j = 0; j < EDIM / 4; ++j) {
    float4 v = p[j];
    s += v.x * v.x; s += v.y * v.y; s += v.z * v.z; s += v.w * v.w;
    uint2 ph;
    ph.x = (unsigned)f2bf(v.x) | ((unsigned)f2bf(v.y) << 16);
    ph.y = (unsigned)f2bf(v.z) | ((unsigned)f2bf(v.w) << 16);
    *(uint2*)(eh + j * 4) = ph;
  }
  e2[c] = s;
}

// ---------------- etrans: embT[k][c] = emb[c][k] (fp32), 64x64 LDS tiles ----------------
__global__ __launch_bounds__(256) void etrans_kernel(const float* __restrict__ emb,
                                                     float* __restrict__ embT) {
  __shared__ float tile[64][65];
  const int bc = blockIdx.x & 15;   // 16 code-tiles
  const int bk = blockIdx.x >> 4;   // 4 k-tiles
  const int c0 = bc * 64, k0 = bk * 64;
  const int r = threadIdx.x >> 2;   // 0..63
  const int q = threadIdx.x & 3;    // 0..3
  #pragma unroll
  for (int j = 0; j < 4; ++j) {
    int kq = q + j * 4;             // float4 col 0..15
    float4 v = *(const float4*)&emb[(size_t)(c0 + r) * EDIM + k0 + kq * 4];
    tile[r][kq * 4 + 0] = v.x; tile[r][kq * 4 + 1] = v.y;
    tile[r][kq * 4 + 2] = v.z; tile[r][kq * 4 + 3] = v.w;
  }
  __syncthreads();
  #pragma unroll
  for (int j = 0; j < 4; ++j) {
    int cq = q + j * 4;             // float4 col in c-dim
    float4 w;
    w.x = tile[cq * 4 + 0][r]; w.y = tile[cq * 4 + 1][r];
    w.z = tile[cq * 4 + 2][r]; w.w = tile[cq * 4 + 3][r];
    *(float4*)&embT[(size_t)(k0 + r) * NEMB + c0 + cq * 4] = w;
  }
}

// ---------------- barrier-free strip argmax (unchanged from R10 — validated) ------------
__global__ __launch_bounds__(512) void argmax_kernel(
    const unsigned short* __restrict__ zhi, const unsigned short* __restrict__ ehi,
    const float* __restrict__ e2, float4* __restrict__ gtop) {
  __shared__ short Bs[128 * 256];   // 64 KB

  const int tid  = threadIdx.x;
  const int w    = tid >> 6;      // wave 0..7
  const int lane = tid & 63;
  const int q    = lane >> 4;     // 0..3
  const int lr   = lane & 15;
  const int b = blockIdx.x;
  const int mchunk = b & 63;
  const int nstrip = b >> 6;
  const int nc = nstrip * 128;
  const int rbase0 = mchunk * 1024;

  // ---- stage B once: instr j writes rows {w*16+j*2, +1} linearly; src pre-swizzled ----
  {
    const int qq = lane & 31;            // quad within row
    const int rj = lane >> 5;            // row within pair
    #pragma unroll
    for (int j = 0; j < 8; ++j) {
      int row = w * 16 + j * 2 + rj;
      int gq = (qq & 24) | ((qq & 7) ^ (row & 7));
      gload_lds16(ehi + (size_t)(nc + row) * EDIM + gq * 8,
                  &Bs[(w * 16 + j * 2) * 256]);
    }
  }

  // per-lane e2 for its 8 columns (constant across iters)
  float e2r[8];
  #pragma unroll
  for (int n = 0; n < 8; ++n) e2r[n] = e2[nc + n * 16 + lr];

  __syncthreads();   // compiler drains vmcnt: B-tile ready. Last barrier in the kernel.

  bf16x8 A[2][8];
  {
    const int rowIt = rbase0 + w * 32;
    #pragma unroll
    for (int ms = 0; ms < 2; ++ms) {
      const unsigned short* zb = zhi + (size_t)(rowIt + ms * 16 + lr) * EDIM + q * 8;
      #pragma unroll
      for (int ks = 0; ks < 8; ++ks)
        A[ms][ks] = *(const bf16x8*)(zb + ks * 32);
    }
  }

  #pragma unroll
  for (int it = 0; it < 4; ++it) {
    const int rowIt = rbase0 + it * 256 + w * 32;
    f32x4 acc[2][8];
    #pragma unroll
    for (int ms = 0; ms < 2; ++ms)
      #pragma unroll
      for (int n = 0; n < 8; ++n)
        acc[ms][n] = (f32x4){0.f, 0.f, 0.f, 0.f};

    #pragma unroll
    for (int ks = 0; ks < 8; ++ks) {
      const int sq = ((ks * 4 + q) & 24) | (((ks * 4 + q) & 7) ^ (lr & 7));
      bf16x8 bfr[8];
      #pragma unroll
      for (int n = 0; n < 8; ++n)
        bfr[n] = *(const bf16x8*)&Bs[(n * 16 + lr) * 256 + sq * 8];
      #pragma unroll
      for (int n = 0; n < 8; ++n)
        #pragma unroll
        for (int ms = 0; ms < 2; ++ms)
          acc[ms][n] = __builtin_amdgcn_mfma_f32_16x16x32_bf16(A[ms][ks], bfr[n], acc[ms][n], 0, 0, 0);
    }

    if (it < 3) {   // A regs dead: load next iter's A; latency hides under epilogue
      const int rowN = rbase0 + (it + 1) * 256 + w * 32;
      #pragma unroll
      for (int ms = 0; ms < 2; ++ms) {
        const unsigned short* zb = zhi + (size_t)(rowN + ms * 16 + lr) * EDIM + q * 8;
        #pragma unroll
        for (int ks = 0; ks < 8; ++ks)
          A[ms][ks] = *(const bf16x8*)(zb + ks * 32);
      }
    }

    // epilogue: top2 over this iter's 32 rows x 128 cols (sim' = e2 - 2*dot)
    float b1[8], b2[8]; int i1[8];
    #pragma unroll
    for (int s = 0; s < 8; ++s) { b1[s] = -3.4e38f; b2[s] = -3.4e38f; i1[s] = 0; }
    #pragma unroll
    for (int n = 0; n < 8; ++n) {
      int c = nc + n * 16 + lr;
      #pragma unroll
      for (int ms = 0; ms < 2; ++ms)
        #pragma unroll
        for (int r = 0; r < 4; ++r) {
          float sim = fmaf(acc[ms][n][r], -2.0f, e2r[n]);
          int s = ms * 4 + r;
          bool gt = sim > b1[s];
          b2[s] = fmaxf(b2[s], gt ? b1[s] : sim);
          if (gt) { b1[s] = sim; i1[s] = c; }
        }
    }
    // cross-lane reduce over 16 col-lanes (masks 1,2,4,8), idx tie-break min
    #pragma unroll
    for (int mask = 1; mask <= 8; mask <<= 1) {
      #pragma unroll
      for (int s = 0; s < 8; ++s) {
        float ov1 = __shfl_xor(b1[s], mask);
        int   oi  = __shfl_xor(i1[s], mask);
        float ov2 = __shfl_xor(b2[s], mask);
        float nb2 = fmaxf(fmaxf(b2[s], ov2), fminf(b1[s], ov1));
        bool take = (ov1 > b1[s]) || (ov1 == b1[s] && oi < i1[s]);
        if (take) { b1[s] = ov1; i1[s] = oi; }
        b2[s] = nb2;
      }
    }
    if (lr == 0) {
      #pragma unroll
      for (int s = 0; s < 8; ++s) {
        int grow = rowIt + (s >> 2) * 16 + q * 4 + (s & 3);   // C-layout row = q*4+reg
        float4 t; t.x = b1[s]; t.y = __int_as_float(i1[s]); t.z = b2[s]; t.w = 0.f;
        gtop[(size_t)grow * 8 + nstrip] = t;
      }
    }
  }
}

// ---------------- merge 8 strip-top2s per row -> idxs + margin worklist ----------------
__global__ __launch_bounds__(256) void merge_kernel(const float4* __restrict__ gtop,
                                                    int* __restrict__ idxs,
                                                    int* __restrict__ cnt,
                                                    int* __restrict__ worklist) {
  int r = blockIdx.x * 256 + threadIdx.x;   // grid 256 -> 65536 rows
  float bv1 = -3.4e38f, bv2 = -3.4e38f; int bi1 = 0;
  #pragma unroll
  for (int s = 0; s < 8; ++s) {
    float4 t = gtop[(size_t)r * 8 + s];
    float v1 = t.x, v2 = t.z; int i = __float_as_int(t.y);
    float nb2 = fmaxf(fmaxf(bv2, v2), fminf(bv1, v1));
    bool take = (v1 > bv1) || (v1 == bv1 && i < bi1);
    if (take) { bv1 = v1; bi1 = i; }
    bv2 = nb2;
  }
  idxs[r] = bi1;
  if (bv1 - bv2 < MARGIN) {
    int p = atomicAdd(cnt, 1);
    worklist[p] = r;
  }
}

// ---------------- exact fp32 rescue, quarter-split: 16 rows x 256 codes per item -------
// item = batch*4 + quarter. Thread (cg=lane, rg=wave): codes c0+4cg..+3, rows 4rg..4rg+3.
// Per k4: 4 LDS b128 broadcast + 4 coalesced float4 (embT) + 64 fma -> VALU-bound,
// dot[4][4]=16 VGPR. fma chain per (row,code) k-ascending scalar == validated R1 chain.
// Quarter-exact top1 -> ptop[row][quarter]; merge2 takes exact cross-quarter argmax.
__global__ __launch_bounds__(256) void rescue_kernel(const float* __restrict__ z,
                                                     const float* __restrict__ embT,
                                                     const float* __restrict__ e2,
                                                     float2* __restrict__ ptop,
                                                     const int* __restrict__ cnt,
                                                     const int* __restrict__ worklist) {
  __shared__ float zr[16][EDIM];     // 16 KB
  __shared__ float z2s[16];
  __shared__ int   rows_s[16];
  const int tid = threadIdx.x;
  const int cg  = tid & 63;          // lane
  const int rg  = tid >> 6;          // wave
  const float4* z4 = (const float4*)z;
  const float4* eT4 = (const float4*)embT;
  const int n = cnt[0];
  const int nitems = ((n + 15) >> 4) << 2;

  for (int item = blockIdx.x; item < nitems; item += gridDim.x) {
    const int batch = item >> 2;
    const int quarter = item & 3;
    const int base = batch * 16;
    const int nr = min(16, n - base);

    __syncthreads();   // prior item's zr reads done before overwrite
    for (int i = tid; i < nr * 64; i += 256) {
      int r = i >> 6, k4 = i & 63;
      int row = worklist[base + r];
      ((float4*)zr[r])[k4] = z4[(size_t)row * 64 + k4];
    }
    if (tid < nr) rows_s[tid] = worklist[base + tid];
    __syncthreads();
    if (tid < nr) {    // per-row ||z||^2, R1-sequential rounding
      float s = 0.f;
      const float4* p = (const float4*)zr[tid];
      for (int k = 0; k < 64; ++k) {
        float4 v = p[k];
        s += v.x * v.x; s += v.y * v.y; s += v.z * v.z; s += v.w * v.w;
      }
      z2s[tid] = s;
    }
    __syncthreads();

    const int c0 = quarter * 256 + cg * 4;
    float dot[4][4];   // [cc][r]
    #pragma unroll
    for (int cc = 0; cc < 4; ++cc)
      #pragma unroll
      for (int r = 0; r < 4; ++r) dot[cc][r] = 0.f;

    for (int k4 = 0; k4 < 64; ++k4) {
      float4 a[4];
      #pragma unroll
      for (int r = 0; r < 4; ++r) a[r] = ((const float4*)zr[rg * 4 + r])[k4];  // bcast
      #pragma unroll
      for (int dk = 0; dk < 4; ++dk) {
        int k = k4 * 4 + dk;
        float4 b = eT4[(size_t)k * 256 + (c0 >> 2)];   // 1KB/wave coalesced
        #pragma unroll
        for (int r = 0; r < 4; ++r) {
          float av = (dk == 0) ? a[r].x : (dk == 1) ? a[r].y : (dk == 2) ? a[r].z : a[r].w;
          dot[0][r] = fmaf(av, b.x, dot[0][r]);
          dot[1][r] = fmaf(av, b.y, dot[1][r]);
          dot[2][r] = fmaf(av, b.z, dot[2][r]);
          dot[3][r] = fmaf(av, b.w, dot[3][r]);
        }
      }
    }

    float bv[4]; int bi[4];
    #pragma unroll
    for (int r = 0; r < 4; ++r) { bv[r] = -3.4e38f; bi[r] = 0; }
    #pragma unroll
    for (int cc = 0; cc < 4; ++cc) {
      int c = c0 + cc;
      float e2v = e2[c];
      #pragma unroll
      for (int r = 0; r < 4; ++r) {
        float t = z2s[rg * 4 + r] + e2v;
        float s = fmaf(dot[cc][r], -2.0f, t);
        if (s > bv[r] || (s == bv[r] && c < bi[r])) { bv[r] = s; bi[r] = c; }
      }
    }

    // in-wave reduce over 64 lanes (all lanes share rows rg*4..rg*4+3)
    #pragma unroll
    for (int mask = 1; mask <= 32; mask <<= 1) {
      #pragma unroll
      for (int r = 0; r < 4; ++r) {
        float ov = __shfl_xor(bv[r], mask);
        int   oi = __shfl_xor(bi[r], mask);
        if (ov > bv[r] || (ov == bv[r] && oi < bi[r])) { bv[r] = ov; bi[r] = oi; }
      }
    }
    if (cg == 0) {
      #pragma unroll
      for (int r = 0; r < 4; ++r) {
        int rr = rg * 4 + r;
        if (rr < nr) {
          float2 t; t.x = bv[r]; t.y = __int_as_float(bi[r]);
          ptop[(size_t)rows_s[rr] * 4 + quarter] = t;
        }
      }
    }
  }
}

// ---------------- merge2: exact cross-quarter argmax for flagged rows ------------------
__global__ __launch_bounds__(256) void merge2_kernel(const float2* __restrict__ ptop,
                                                     int* __restrict__ idxs,
                                                     const int* __restrict__ cnt,
                                                     const int* __restrict__ worklist) {
  int i = blockIdx.x * 256 + threadIdx.x;   // grid 256 covers 65536
  if (i >= cnt[0]) return;
  int row = worklist[i];
  float bv = -3.4e38f; int bi = 0x7fffffff;
  #pragma unroll
  for (int qr = 0; qr < 4; ++qr) {
    float2 t = ptop[(size_t)row * 4 + qr];
    float v = t.x; int idx = __float_as_int(t.y);
    if (v > bv || (v == bv && idx < bi)) { bv = v; bi = idx; }
  }
  idxs[row] = bi;
}

// ---------------- gather z_q + squared-diff partial sums + idxf ----------------
__global__ __launch_bounds__(256) void gather_kernel(
    const float* __restrict__ z, const float* __restrict__ emb,
    const int* __restrict__ idxs, float* __restrict__ out,
    float* __restrict__ partials, float* __restrict__ idxf) {
  const int tid = threadIdx.x;
  const int b = blockIdx.x;            // 1024 blocks, 64 rows each
  const float4* z4 = (const float4*)z;
  float4* q4 = (float4*)out;

  if (tid < 64) {
    int r2 = b * 64 + tid;
    idxf[r2] = (float)idxs[r2];
  }

  float acc = 0.f;
  #pragma unroll
  for (int i = 0; i < 16; ++i) {
    int f = b * 4096 + tid + 256 * i;  // float4 index
    int row = f >> 6;
    int c4 = f & 63;
    int e = idxs[row];
    float4 ev = *(const float4*)&emb[(size_t)e * EDIM + 4 * c4];
    float4 zv = z4[f];
    q4[f] = ev;
    float dx = ev.x - zv.x, dy = ev.y - zv.y, dz = ev.z - zv.z, dw = ev.w - zv.w;
    acc += dx * dx + dy * dy + dz * dz + dw * dw;
  }
  __shared__ float red[256];
  red[tid] = acc;
  __syncthreads();
  #pragma unroll
  for (int sN = 128; sN > 0; sN >>= 1) {
    if (tid < sN) red[tid] += red[tid + sN];
    __syncthreads();
  }
  if (tid == 0) partials[b] = red[0];
}

__global__ void finalize_kernel(const float* __restrict__ partials,
                                float* __restrict__ out) {
  if (threadIdx.x == 0 && blockIdx.x == 0) {
    double s = 0.0;
    for (int i = 0; i < 1024; ++i) s += (double)partials[i];
    float m = (float)(s / 16777216.0);
    out[OUT_VQ] = m;
    out[OUT_CM] = 0.25f * m;
  }
}

extern "C" void kernel_launch(void* const* d_in, const int* in_sizes, int n_in,
                              void* d_out, int out_size, void* d_ws, size_t ws_size,
                              hipStream_t stream) {
  const float* z   = (const float*)d_in[0];
  const float* emb = (const float*)d_in[1];
  float* out = (float*)d_out;

  // d_out z_q region (64MB) staging, overwritten by gather afterwards:
  //   zhi bf16 [0,32MB) | embT fp32 [32,33MB) | gtop float4 [36,44MB) | ptop [44,46MB)
  unsigned short* zhi = (unsigned short*)d_out;
  float* embT = out + 8388608;
  float4* gtop = (float4*)(out + 9437184);
  float2* ptop = (float2*)(out + 11534336);

  // ws: ehi 512KB | e2 4KB | idxs 256KB | partials 4KB | cnt 16B | worklist 256KB
  unsigned short* ehi = (unsigned short*)d_ws;
  float* e2       = (float*)(ehi + 262144);
  int*   idxs     = (int*)(e2 + 1024);
  float* partials = (float*)(idxs + 65536);
  int*   cnt      = (int*)(partials + 1024);
  int*   worklist = cnt + 4;

  zsplit_kernel<<<8192, 256, 0, stream>>>(z, zhi);
  eprep_kernel<<<NEMB / 256, 256, 0, stream>>>(emb, ehi, e2, cnt);
  etrans_kernel<<<64, 256, 0, stream>>>(emb, embT);
  argmax_kernel<<<512, 512, 0, stream>>>(zhi, ehi, e2, gtop);
  merge_kernel<<<256, 256, 0, stream>>>(gtop, idxs, cnt, worklist);
  rescue_kernel<<<2048, 256, 0, stream>>>(z, embT, e2, ptop, cnt, worklist);
  merge2_kernel<<<256, 256, 0, stream>>>(ptop, idxs, cnt, worklist);
  gather_kernel<<<1024, 256, 0, stream>>>(z, emb, idxs, out, partials, out + OUT_IDX);
  finalize_kernel<<<1, 64, 0, stream>>>(partials, out);
}